// Round 15
// baseline (1822.387 us; speedup 1.0000x reference)
//
#include <hip/hip_runtime.h>

#define BB 8
#define NN 4096
#define KK 20
constexpr float EPSV = 1e-5f;
constexpr float SLOPE = 0.2f;

typedef __bf16 bfrag __attribute__((ext_vector_type(8)));
typedef float floatx4 __attribute__((ext_vector_type(4)));
typedef unsigned short us4 __attribute__((ext_vector_type(4)));
typedef unsigned short us8 __attribute__((ext_vector_type(8)));

__device__ __forceinline__ float lrelu(float v) { return v >= 0.f ? v : SLOPE * v; }

__device__ __forceinline__ unsigned short bf16rn(float f) {
    unsigned int u = __float_as_uint(f);
    return (unsigned short)((u + 0x7FFFu + ((u >> 16) & 1u)) >> 16);
}
__device__ __forceinline__ float bf16up(unsigned short h) {
    return __uint_as_float(((unsigned int)h) << 16);
}

// async global->LDS DMA, 16B per lane; lds dest must be wave-uniform base.
__device__ __forceinline__ void gl_lds16(const unsigned short* g, unsigned short* l) {
    __builtin_amdgcn_global_load_lds((const __attribute__((address_space(1))) void*)g,
                                     (__attribute__((address_space(3))) void*)l, 16, 0, 0);
}

__global__ void zero_kernel(float* p, int n) {
    int i = blockIdx.x * 256 + threadIdx.x;
    if (i < n) p[i] = 0.f;
}

// C=3 B-pack: [h3 l3 l3 h3 | 0 x20 | hn fp32 | 0 x6] per point (SK=40), hn inline.
__global__ void pack3_kernel(const float* __restrict__ src, unsigned short* __restrict__ pk) {
    const int id = blockIdx.x;
    const int b = id & 7;
    const int m = (id >> 3) * 256 + threadIdx.x;
    us8 w0, w1;
    #pragma unroll
    for (int j = 0; j < 8; j++) { w0[j] = 0; w1[j] = 0; }
    unsigned short row[12];
    float s = 0.f;
    #pragma unroll
    for (int c = 0; c < 3; c++) {
        float v = src[(b * 3 + c) * NN + m];
        s += v * v;
        unsigned short h = bf16rn(v);
        unsigned short l = bf16rn(v - bf16up(h));
        row[c] = h; row[3 + c] = l; row[6 + c] = l; row[9 + c] = h;
    }
    #pragma unroll
    for (int j = 0; j < 8; j++) w0[j] = row[j];
    #pragma unroll
    for (int j = 0; j < 4; j++) w1[j] = row[8 + j];
    unsigned short* dst = pk + (size_t)(b * NN + m) * 40;
    us8 z;
    #pragma unroll
    for (int j = 0; j < 8; j++) z[j] = 0;
    unsigned int ub = __float_as_uint(0.5f * s);
    us8 zh = z;
    zh[0] = (unsigned short)(ub & 0xFFFFu);
    zh[1] = (unsigned short)(ub >> 16);
    *(us8*)(dst) = w0;
    *(us8*)(dst + 8) = w1;
    *(us8*)(dst + 16) = z;
    *(us8*)(dst + 24) = z;
    *(us8*)(dst + 32) = zh;
}

// ---------------- kNN via MFMA (bf16 hi/lo split, 4-term exact) ----------------
// ROUND-7 VERBATIM (best measured: 254us C=64). 64 q/block, 2 blocks/CU,
// double-buffered global_load_lds staging, hn in row pad, exact running tau,
// pool + tid<64 drain, 2 __syncthreads per chunk, XCD pinning.
template<int C>
__global__ __launch_bounds__(256) void knn_kernel(const float* __restrict__ src,
                                                  const unsigned short* __restrict__ pk,
                                                  int* __restrict__ idx) {
    constexpr int SK = (C == 3) ? 40 : (2 * C + 8);   // padded k-stride (shorts)
    constexpr int HNOFF = (C == 3) ? 32 : 2 * C;      // hn fp32 offset in row
    constexpr int UNITS = 8 * SK;                     // 16B units per 64-row chunk
    constexpr int PF = (UNITS + 255) / 256;
    constexpr int KKN = (C == 3) ? 1 : (C / 32);
    __shared__ __attribute__((aligned(16))) unsigned short cpack[2 * 64 * SK];
    __shared__ float pv[64 * 65];
    __shared__ unsigned short pidx[64 * 66];
    __shared__ float tau[64];
    __shared__ int cnt[64];
    __shared__ unsigned short qls[(C == 3) ? 64 * 40 : 2];

    const int bid = blockIdx.x;
    const int b = bid & 7;               // batch -> XCD (wgid % 8 round-robin)
    const int q0 = (bid >> 3) * 64;
    const int tid = threadIdx.x;
    const int lane = tid & 63;
    const int wv = tid >> 6;
    const int wr = (wv >> 1) * 32;      // wave q-offset in [0,64)
    const int wc = (wv & 1) * 32;       // wave m-offset in [0,64)
    const int fl = lane & 15;
    const int fq = lane >> 4;

    float tv[20]; int ti[20];
    #pragma unroll
    for (int k = 0; k < 20; k++) { tv[k] = -3.4e38f; ti[k] = 0; }

    // ---- A fragments (registers, once) ----
    bfrag qah[KKN][2], qal[KKN][2];
    if (C == 3) {
        for (int i = tid; i < 64 * 20; i += 256) {
            int r = i / 20, k = 12 + i % 20;
            qls[r * 40 + k] = 0;
        }
        if (tid < 64) {
            #pragma unroll
            for (int c = 0; c < 3; c++) {
                float v = src[(b * 3 + c) * NN + q0 + tid];
                unsigned short h = bf16rn(v);
                unsigned short l = bf16rn(v - bf16up(h));
                // A-pack: [h3 l3 h3 l3 | 0...] pairs with B-pack [h3 l3 l3 h3]
                qls[tid * 40 + c] = h;  qls[tid * 40 + 3 + c] = l;
                qls[tid * 40 + 6 + c] = h;  qls[tid * 40 + 9 + c] = l;
            }
        }
    } else {
        #pragma unroll
        for (int r2 = 0; r2 < 2; r2++) {
            const unsigned short* qr = pk + (size_t)(b * NN + q0 + wr + r2 * 16 + fl) * SK + fq * 8;
            #pragma unroll
            for (int kk = 0; kk < KKN; kk++) {
                qah[kk][r2] = *(const bfrag*)(qr + kk * 32);
                qal[kk][r2] = *(const bfrag*)(qr + C + kk * 32);
            }
        }
    }

    // ---- prologue: async-stage chunk 0 into buffer 0 ----
    {
        const unsigned short* p0 = pk + (size_t)(b * NN) * SK;
        #pragma unroll
        for (int r = 0; r < PF; r++) {
            int u0 = r * 256 + wv * 64;          // wave-uniform base unit
            if (u0 < UNITS)
                gl_lds16(p0 + (size_t)(u0 + lane) * 8, cpack + (size_t)u0 * 8);
        }
    }
    if (tid < 64) { tau[tid] = -3.4e38f; cnt[tid] = 0; }
    __syncthreads();    // drains vmcnt: chunk 0 resident

    bfrag qa3[2];
    if (C == 3) {
        #pragma unroll
        for (int r2 = 0; r2 < 2; r2++)
            qa3[r2] = *(const bfrag*)(&qls[(wr + r2 * 16 + fl) * 40 + fq * 8]);
    }

    int buf = 0;
    for (int ch = 0; ch < 64; ch++) {
        unsigned short* cur = cpack + buf * (64 * SK);
        // ---- Phase A: issue async stage of ch+1; MFMA + filter on cur ----
        if (ch + 1 < 64) {
            unsigned short* nxt = cpack + (buf ^ 1) * (64 * SK);
            const unsigned short* pn = pk + (size_t)(b * NN + (ch + 1) * 64) * SK;
            #pragma unroll
            for (int r = 0; r < PF; r++) {
                int u0 = r * 256 + wv * 64;
                if (u0 < UNITS)
                    gl_lds16(pn + (size_t)(u0 + lane) * 8, nxt + (size_t)u0 * 8);
            }
        }

        floatx4 acc[2][2];
        #pragma unroll
        for (int r2 = 0; r2 < 2; r2++)
            #pragma unroll
            for (int c2 = 0; c2 < 2; c2++)
                acc[r2][c2] = (floatx4)(0.f);

        if (C == 3) {
            #pragma unroll
            for (int c2 = 0; c2 < 2; c2++) {
                bfrag bm = *(const bfrag*)(&cur[(wc + c2 * 16 + fl) * SK + fq * 8]);
                #pragma unroll
                for (int r2 = 0; r2 < 2; r2++)
                    acc[r2][c2] = __builtin_amdgcn_mfma_f32_16x16x32_bf16(qa3[r2], bm, acc[r2][c2], 0, 0, 0);
            }
        } else {
            #pragma unroll
            for (int kk = 0; kk < KKN; kk++) {
                const int kb = kk * 32 + fq * 8;
                bfrag bh[2], bl[2];
                #pragma unroll
                for (int c2 = 0; c2 < 2; c2++) {
                    bh[c2] = *(const bfrag*)(&cur[(wc + c2 * 16 + fl) * SK + kb]);
                    bl[c2] = *(const bfrag*)(&cur[(wc + c2 * 16 + fl) * SK + C + kb]);
                }
                #pragma unroll
                for (int r2 = 0; r2 < 2; r2++)
                    #pragma unroll
                    for (int c2 = 0; c2 < 2; c2++) {
                        acc[r2][c2] = __builtin_amdgcn_mfma_f32_16x16x32_bf16(qah[kk][r2], bh[c2], acc[r2][c2], 0, 0, 0);
                        acc[r2][c2] = __builtin_amdgcn_mfma_f32_16x16x32_bf16(qah[kk][r2], bl[c2], acc[r2][c2], 0, 0, 0);
                        acc[r2][c2] = __builtin_amdgcn_mfma_f32_16x16x32_bf16(qal[kk][r2], bh[c2], acc[r2][c2], 0, 0, 0);
                        acc[r2][c2] = __builtin_amdgcn_mfma_f32_16x16x32_bf16(qal[kk][r2], bl[c2], acc[r2][c2], 0, 0, 0);
                    }
            }
        }

        // ---- filter: C-layout col=lane&15 (m), row=fq*4+reg (q); exact tau;
        //      hn read from the staged row pad in LDS ----
        {
            const int m0 = ch * 64;
            float hvv[2];
            #pragma unroll
            for (int c2 = 0; c2 < 2; c2++)
                hvv[c2] = *(const float*)(&cur[(wc + c2 * 16 + fl) * SK + HNOFF]);
            #pragma unroll
            for (int r2 = 0; r2 < 2; r2++) {
                const int qb = wr + r2 * 16 + fq * 4;
                float4 t4 = *(const float4*)(&tau[qb]);
                float ta[4] = { t4.x, t4.y, t4.z, t4.w };
                #pragma unroll
                for (int c2 = 0; c2 < 2; c2++) {
                    const float hv = hvv[c2];
                    const int mm = m0 + wc + c2 * 16 + fl;
                    #pragma unroll
                    for (int reg = 0; reg < 4; reg++) {
                        float s = acc[r2][c2][reg] - hv;
                        if (s > ta[reg]) {
                            int q = qb + reg;
                            int p = atomicAdd(&cnt[q], 1);   // <= 64 per chunk: fits
                            pv[q * 65 + p] = s;
                            pidx[q * 66 + p] = (unsigned short)mm;
                        }
                    }
                }
            }
        }
        __syncthreads();   // B1: pool complete; vmcnt(0) -> next chunk resident

        // ---- Phase B: drain (tid<64, lane-parallel over q); exact top-20 + tau ----
        if (tid < 64) {
            int n = cnt[tid];
            for (int t = 0; t < n; t++) {
                float v = pv[tid * 65 + t];
                if (v > tv[0]) {
                    tv[0] = v; ti[0] = (int)pidx[tid * 66 + t];
                    #pragma unroll
                    for (int j = 0; j < 19; j++) {
                        if (tv[j] > tv[j + 1]) {
                            float a = tv[j]; tv[j] = tv[j + 1]; tv[j + 1] = a;
                            int bi = ti[j]; ti[j] = ti[j + 1]; ti[j + 1] = bi;
                        }
                    }
                }
            }
            cnt[tid] = 0;
            tau[tid] = tv[0];
        }
        __syncthreads();   // B2: tau/cnt ready
        buf ^= 1;
    }

    if (tid < 64) {
        #pragma unroll
        for (int k = 0; k < 20; k++)
            idx[(b * NN + q0 + tid) * KK + k] = ti[k];   // order irrelevant downstream
    }
}

// ---------------- conv precompute: G = Wd*src, H = (Wc-Wd)*src ----------------
// XCD-pinned: b = blockIdx.x & 7. (used for conv1 and convd2)
template<int COUT>
__global__ void precompute_kernel(const float* __restrict__ src, int C,
                                  const float* __restrict__ w, int CIN, int wd_off, int wc_off,
                                  float* __restrict__ G, float* __restrict__ H) {
    constexpr int MY = 256 / COUT;
    extern __shared__ float lds[];
    float* wd = lds;
    float* wc = lds + C * COUT;
    const int id = blockIdx.x;
    const int b = id & 7;
    const int m_base = (id >> 3) * 64;
    const int tid = threadIdx.y * COUT + threadIdx.x;
    for (int i = tid; i < C * COUT; i += 256) {
        int c = i / COUT, o = i % COUT;
        float a  = w[o * CIN + wd_off + c];
        float cc = w[o * CIN + wc_off + c];
        wd[i] = a;
        wc[i] = cc - a;
    }
    __syncthreads();
    const int o = threadIdx.x;
    for (int it = 0; it < COUT / 4; it++) {
        int m = m_base + it * MY + threadIdx.y;
        float g = 0.f, h = 0.f;
        for (int c = 0; c < C; c++) {
            float s = src[(b * C + c) * NN + m];
            g += wd[c * COUT + o] * s;
            h += wc[c * COUT + o] * s;
        }
        int gi = (b * NN + m) * COUT + o;
        G[gi] = g;
        H[gi] = h;
    }
}

// conv2 + convd1 fused precompute: one pass over x (3ch) and x1m (32ch) emits
//   GA = w2_dA*x, GB = w2_dB*x1m, H2 = (w2_c-w2_d)*(x,x1m)   [conv2]
//   Gd1 = wd1_d*x1m, Hd1 = (wd1_c-wd1_d)*x1m                  [convd1]
// Saves one dispatch + one x1m pass. XCD-pinned.
__global__ void precompute2x_kernel(const float* __restrict__ srcA, const float* __restrict__ srcB,
                                    const float* __restrict__ w2, const float* __restrict__ wd1w,
                                    float* __restrict__ GA, float* __restrict__ GB,
                                    float* __restrict__ H2,
                                    float* __restrict__ Gd1, float* __restrict__ Hd1) {
    constexpr int COUT = 64, CA = 3, CB = 32;
    __shared__ float wdA[CA * COUT], wcA[CA * COUT];
    __shared__ float wdB[CB * COUT], wcB[CB * COUT];
    __shared__ float wdD[CB * COUT], wcD[CB * COUT];
    const int id = blockIdx.x;
    const int b = id & 7;
    const int m_base = (id >> 3) * 64;
    const int tid = threadIdx.y * COUT + threadIdx.x;
    for (int i = tid; i < CA * COUT; i += 256) {
        int c = i / COUT, o = i % COUT;
        float a = w2[o * 70 + c], cc = w2[o * 70 + 3 + c];
        wdA[i] = a; wcA[i] = cc - a;
    }
    for (int i = tid; i < CB * COUT; i += 256) {
        int c = i / COUT, o = i % COUT;
        float a = w2[o * 70 + 6 + c], cc = w2[o * 70 + 38 + c];
        wdB[i] = a; wcB[i] = cc - a;
        float ad = wd1w[o * 64 + c], cd = wd1w[o * 64 + 32 + c];
        wdD[i] = ad; wcD[i] = cd - ad;
    }
    __syncthreads();
    const int o = threadIdx.x;
    for (int it = 0; it < 16; it++) {
        int m = m_base + it * 4 + threadIdx.y;
        float ga = 0.f, h2 = 0.f;
        for (int c = 0; c < CA; c++) {
            float s = srcA[(b * CA + c) * NN + m];
            ga += wdA[c * COUT + o] * s;
            h2 += wcA[c * COUT + o] * s;
        }
        float gb = 0.f, gd = 0.f, hd = 0.f;
        for (int c = 0; c < CB; c++) {
            float s = srcB[(b * CB + c) * NN + m];
            gb += wdB[c * COUT + o] * s;
            h2 += wcB[c * COUT + o] * s;
            gd += wdD[c * COUT + o] * s;
            hd += wcD[c * COUT + o] * s;
        }
        size_t gi = (size_t)(b * NN + m) * COUT + o;
        GA[gi] = ga;
        GB[gi] = gb;
        H2[gi] = h2;
        Gd1[gi] = gd;
        Hd1[gi] = hd;
    }
}

// ---------------- conv stats + per-(b,n,o) selected extreme over k -------------
// sign(sc) = sign(g[o]) (rsqrt > 0): write single V = chosen extreme + h.
// XCD-pinned: b = blockIdx.x & 7 -> batch-b G-rows L2-resident.
template<int COUT, int GROUPS>
__global__ void conv_stats_kernel(const float* __restrict__ G1, const int* __restrict__ idx1,
                                  const float* __restrict__ G2, const int* __restrict__ idx2,
                                  const float* __restrict__ H, const float* __restrict__ gw,
                                  float* __restrict__ stats, float* __restrict__ V) {
    constexpr int NY = 256 / COUT;
    const int id = blockIdx.x;
    const int b = id & 7;
    const int o = threadIdx.x;
    const int n = (id >> 3) * NY + threadIdx.y;
    const int base = b * NN + n;
    const float h = H[base * COUT + o];
    float s1 = 0.f, s2 = 0.f;
    float gx = -3.4e38f, gn = 3.4e38f;
    #pragma unroll
    for (int k = 0; k < KK; k++) {
        int i1 = idx1[base * KK + k];
        float g = G1[(b * NN + i1) * COUT + o];
        if (GROUPS == 2) {
            int i2 = idx2[base * KK + k];
            g += G2[(b * NN + i2) * COUT + o];
        }
        float y = g + h;
        s1 += y;
        s2 += y * y;
        gx = fmaxf(gx, g);
        gn = fminf(gn, g);
    }
    V[base * COUT + o] = ((gw[o] >= 0.f) ? gx : gn) + h;

    __shared__ float ls[2 * COUT];
    if (threadIdx.y == 0) { ls[o] = 0.f; ls[COUT + o] = 0.f; }
    __syncthreads();
    atomicAdd(&ls[o], s1);
    atomicAdd(&ls[COUT + o], s2);
    __syncthreads();
    if (threadIdx.y == 0) {
        atomicAdd(&stats[o], ls[o]);
        atomicAdd(&stats[64 + o], ls[COUT + o]);
    }
}

// ---------------- FUSED apply + pack (for x1m, x2m) ----------------
// Reads V, applies BN affine + lrelu (finalize fused), writes BOTH the fp32
// tensor xm AND the bf16 hi/lo packed rows + hn pad for the next kNN.
// Pad region [2C+2,2C+8) of each pk row is never read -> left unwritten.
// XCD-pinned: b = blockIdx.x & 7; block covers 64 points x COUT channels.
template<int COUT>
__global__ void applypack_kernel(const float* __restrict__ V, const float* __restrict__ stats,
                                 const float* __restrict__ g, const float* __restrict__ bb,
                                 float* __restrict__ xm, unsigned short* __restrict__ pk,
                                 float invP) {
    constexpr int SK = 2 * COUT + 8;
    constexpr int Q = COUT / 4;          // channels per thread (4 threads/point)
    __shared__ float sc_s[COUT], sh_s[COUT], hnacc[64];
    const int id = blockIdx.x;
    const int b = id & 7;
    const int m0 = (id >> 3) * 64;
    const int tid = threadIdx.x;
    if (tid < COUT) {
        float mu  = stats[tid] * invP;
        float var = stats[64 + tid] * invP - mu * mu;
        float sc  = g[tid] * rsqrtf(var + EPSV);
        sc_s[tid] = sc;
        sh_s[tid] = bb[tid] - mu * sc;
    }
    if (tid < 64) hnacc[tid] = 0.f;
    __syncthreads();
    const int n = tid & 63;
    const int oc = (tid >> 6) * Q;
    const float* vp = V + ((size_t)(b * NN + m0 + n) * COUT + oc);
    float y[Q];
    float s = 0.f;
    #pragma unroll
    for (int j = 0; j < Q; j++) {
        float yy = lrelu(sc_s[oc + j] * vp[j] + sh_s[oc + j]);
        y[j] = yy;
        s += yy * yy;
        xm[(b * COUT + oc + j) * NN + m0 + n] = yy;
    }
    atomicAdd(&hnacc[n], s);
    unsigned short* pr = pk + (size_t)(b * NN + m0 + n) * SK;
    #pragma unroll
    for (int j4 = 0; j4 < Q / 4; j4++) {
        us4 hv, lv;
        #pragma unroll
        for (int j = 0; j < 4; j++) {
            float yy = y[j4 * 4 + j];
            unsigned short h = bf16rn(yy);
            hv[j] = h;
            lv[j] = bf16rn(yy - bf16up(h));
        }
        *(us4*)(pr + oc + j4 * 4) = hv;
        *(us4*)(pr + COUT + oc + j4 * 4) = lv;
    }
    __syncthreads();
    if (tid < 64)
        *(unsigned int*)(pk + (size_t)(b * NN + m0 + tid) * SK + 2 * COUT) =
            __float_as_uint(0.5f * hnacc[tid]);
}

// ---------------- FUSED apply + mean-reduce (for xd1/xd2; arrays eliminated) ---
// Computes y = lrelu(sc*V+sh) with o-FAST coalesced V reads (wave = one n,
// lanes = 64 channels), wave-shuffle-reduces the channel sum, accumulates into
// hsum[n & 127] (identical binning to the old mean kernel: channel offsets are
// multiples of 4096 so e&127 == n&127). XCD-pinned. 1024 blocks.
__global__ void applyreduce_kernel(const float* __restrict__ V, const float* __restrict__ stats,
                                   const float* __restrict__ g, const float* __restrict__ bb,
                                   float* __restrict__ hsum, float invP) {
    __shared__ float sc_s[64], sh_s[64];
    const int id = blockIdx.x;          // b = id&7, slice = id>>3 in [0,128)
    const int b = id & 7;
    const int slice = id >> 3;
    const int tid = threadIdx.x;
    const int o = tid & 63;
    const int wvn = tid >> 6;           // wave -> n sub-index
    if (tid < 64) {
        float mu  = stats[tid] * invP;
        float var = stats[64 + tid] * invP - mu * mu;
        float sc  = g[tid] * rsqrtf(var + EPSV);
        sc_s[tid] = sc;
        sh_s[tid] = bb[tid] - mu * sc;
    }
    __syncthreads();
    for (int it = 0; it < 8; it++) {
        int n = slice * 32 + it * 4 + wvn;
        float v = V[((size_t)(b * NN + n)) * 64 + o];
        float y = lrelu(sc_s[o] * v + sh_s[o]);
        #pragma unroll
        for (int s = 32; s > 0; s >>= 1) y += __shfl_down(y, s, 64);
        if (o == 0) atomicAdd(&hsum[n & 127], y);
    }
}

__global__ void head_kernel(const float* __restrict__ hsum,
                            const float* __restrict__ W2d, const float* __restrict__ b2d,
                            const float* __restrict__ W3d, const float* __restrict__ b3d,
                            const float* __restrict__ W4d, const float* __restrict__ b4d,
                            float* __restrict__ out) {
    __shared__ float h[128], t1[128], t2[64];
    const int t = threadIdx.x;
    h[t] = hsum[t] * (1.f / 32768.f);
    __syncthreads();
    float a = b2d[t];
    for (int j = 0; j < 128; j++) a += W2d[t * 128 + j] * h[j];
    t1[t] = lrelu(a);
    __syncthreads();
    if (t < 64) {
        float a2 = b3d[t];
        for (int j = 0; j < 128; j++) a2 += W3d[t * 128 + j] * t1[j];
        t2[t] = lrelu(a2);
    }
    __syncthreads();
    if (t < 11) {
        float a3 = b4d[t];
        for (int j = 0; j < 64; j++) a3 += W4d[t * 64 + j] * t2[j];
        out[t] = lrelu(a3);
    }
}

extern "C" void kernel_launch(void* const* d_in, const int* in_sizes, int n_in,
                              void* d_out, int out_size, void* d_ws, size_t ws_size,
                              hipStream_t stream) {
    const float* x   = (const float*)d_in[0];
    const float* w1  = (const float*)d_in[1];
    const float* g1  = (const float*)d_in[2];
    const float* b1  = (const float*)d_in[3];
    const float* w2  = (const float*)d_in[4];
    const float* g2  = (const float*)d_in[5];
    const float* b2  = (const float*)d_in[6];
    const float* wd1 = (const float*)d_in[7];
    const float* gd1 = (const float*)d_in[8];
    const float* bd1 = (const float*)d_in[9];
    const float* wd2 = (const float*)d_in[10];
    const float* gd2 = (const float*)d_in[11];
    const float* bd2 = (const float*)d_in[12];
    const float* W2d = (const float*)d_in[13];
    const float* b2d = (const float*)d_in[14];
    const float* W3d = (const float*)d_in[15];
    const float* b3d = (const float*)d_in[16];
    const float* W4d = (const float*)d_in[17];
    const float* b4d = (const float*)d_in[18];
    float* out = (float*)d_out;

    char* ws = (char*)d_ws;
    size_t off = 0;
    auto alloc = [&](size_t bytes) { char* p = ws + off; off += (bytes + 255) & ~size_t(255); return p; };
    int*   idx1  = (int*)  alloc(BB * NN * KK * 4);
    int*   idx2  = (int*)  alloc(BB * NN * KK * 4);
    int*   idx3  = (int*)  alloc(BB * NN * KK * 4);
    float* x1m   = (float*)alloc(BB * 32 * NN * 4);
    float* x2m   = (float*)alloc(BB * 64 * NN * 4);
    float* G1    = (float*)alloc((size_t)BB * NN * 64 * 4);   // contiguous with G2 (pk64 spill)
    float* G2    = (float*)alloc((size_t)BB * NN * 64 * 4);
    float* H     = (float*)alloc((size_t)BB * NN * 64 * 4);
    float* Vbuf  = (float*)alloc((size_t)BB * NN * 64 * 4);
    float* Gd1   = (float*)alloc((size_t)BB * NN * 64 * 4);   // replaces xd1
    float* Hd1   = (float*)alloc((size_t)BB * NN * 64 * 4);   // replaces xd2
    float* stats = (float*)alloc(4 * 256 * 4);    // 4 slabs: conv1/conv2/convd1/convd2
    float* hsum  = (float*)alloc(128 * 4);

    float* st0 = stats;
    float* st1 = stats + 256;
    float* st2 = stats + 512;
    float* st3 = stats + 768;

    // pk placements (dead-buffer reuse, verified under stream order):
    //  pk3  (2.6MB) -> Vbuf   (Vbuf first written by conv1 stats, after knn3)
    //  pk32 (4.7MB) -> G2     (G2 next written by pre2x, after knn32)
    //  pk64 (8.9MB) -> G1 + 0.5MB spill into G2 head (G1/G2 dead after conv2
    //                  stats; knn64 runs before pre-d2 rewrites G1)
    unsigned short* pk3  = (unsigned short*)Vbuf;
    unsigned short* pk32 = (unsigned short*)G2;
    unsigned short* pk64 = (unsigned short*)G1;

    const float invP = 1.f / (float)(BB * NN * KK);
    const dim3 knn_grid(NN / 64 * BB);     // 1D: b = id & 7 (XCD pinning)
    const dim3 pre_grid(NN / 64 * BB);

    // one upfront zero: 4 stats slabs (1024 floats) + hsum (128), contiguous.
    zero_kernel<<<5, 256, 0, stream>>>(stats, 1024 + 128);

    // --- kNN on x (C=3) ---
    pack3_kernel<<<NN / 256 * BB, 256, 0, stream>>>(x, pk3);
    knn_kernel<3><<<knn_grid, 256, 0, stream>>>(x, pk3, idx1);

    // --- conv1: Cout=32, group (x, idx1, C=3), w1 CIN=6 ---
    precompute_kernel<32><<<pre_grid, dim3(32, 8), 2 * 3 * 32 * 4, stream>>>(
        x, 3, w1, 6, 0, 3, G1, H);
    conv_stats_kernel<32, 1><<<NN / 8 * BB, dim3(32, 8), 0, stream>>>(
        G1, idx1, nullptr, nullptr, H, g1, st0, Vbuf);
    applypack_kernel<32><<<pre_grid, 256, 0, stream>>>(Vbuf, st0, g1, b1, x1m, pk32, invP);

    // --- kNN on x1_max (C=32) ---
    knn_kernel<32><<<knn_grid, 256, 0, stream>>>(x1m, pk32, idx2);

    // --- conv2 + convd1 precompute (fused single pass over x, x1m) ---
    precompute2x_kernel<<<pre_grid, dim3(64, 4), 0, stream>>>(
        x, x1m, w2, wd1, G1, G2, H, Gd1, Hd1);
    // --- conv2 stats + applypack ---
    conv_stats_kernel<64, 2><<<NN / 4 * BB, dim3(64, 4), 0, stream>>>(
        G1, idx1, G2, idx2, H, g2, st1, Vbuf);
    applypack_kernel<64><<<pre_grid, 256, 0, stream>>>(Vbuf, st1, g2, b2, x2m, pk64, invP);

    // --- kNN on x2_max (C=64): before pre-d2 (which rewrites G1 = pk64) ---
    knn_kernel<64><<<knn_grid, 256, 0, stream>>>(x2m, pk64, idx3);

    // --- convd1 stats + apply-reduce (xd1 never materialized) ---
    conv_stats_kernel<64, 1><<<NN / 4 * BB, dim3(64, 4), 0, stream>>>(
        Gd1, idx2, nullptr, nullptr, Hd1, gd1, st2, Vbuf);
    applyreduce_kernel<<<1024, 256, 0, stream>>>(Vbuf, st2, gd1, bd1, hsum, invP);

    // --- convd2: precompute + stats + apply-reduce (xd2 never materialized) ---
    precompute_kernel<64><<<pre_grid, dim3(64, 4), 2 * 64 * 64 * 4, stream>>>(
        x2m, 64, wd2, 128, 0, 64, G1, H);
    conv_stats_kernel<64, 1><<<NN / 4 * BB, dim3(64, 4), 0, stream>>>(
        G1, idx3, nullptr, nullptr, H, gd2, st3, Vbuf);
    applyreduce_kernel<<<1024, 256, 0, stream>>>(Vbuf, st3, gd2, bd2, hsum, invP);

    // --- MLP head ---
    head_kernel<<<1, 128, 0, stream>>>(hsum, W2d, b2d, W3d, b3d, W4d, b4d, out);
}

// Round 16
// 1626.441 us; speedup vs baseline: 1.1205x; 1.1205x over previous
//
#include <hip/hip_runtime.h>

#define BB 8
#define NN 4096
#define KK 20
constexpr float EPSV = 1e-5f;
constexpr float SLOPE = 0.2f;

typedef __bf16 bfrag __attribute__((ext_vector_type(8)));
typedef float floatx4 __attribute__((ext_vector_type(4)));
typedef unsigned short us4 __attribute__((ext_vector_type(4)));
typedef unsigned short us8 __attribute__((ext_vector_type(8)));

__device__ __forceinline__ float lrelu(float v) { return v >= 0.f ? v : SLOPE * v; }

__device__ __forceinline__ unsigned short bf16rn(float f) {
    unsigned int u = __float_as_uint(f);
    return (unsigned short)((u + 0x7FFFu + ((u >> 16) & 1u)) >> 16);
}
__device__ __forceinline__ float bf16up(unsigned short h) {
    return __uint_as_float(((unsigned int)h) << 16);
}

// async global->LDS DMA, 16B per lane; lds dest must be wave-uniform base.
__device__ __forceinline__ void gl_lds16(const unsigned short* g, unsigned short* l) {
    __builtin_amdgcn_global_load_lds((const __attribute__((address_space(1))) void*)g,
                                     (__attribute__((address_space(3))) void*)l, 16, 0, 0);
}

__global__ void zero_kernel(float* p, int n) {
    int i = blockIdx.x * 256 + threadIdx.x;
    if (i < n) p[i] = 0.f;
}

// C=3 B-pack: [h3 l3 l3 h3 | 0 x20 | hn fp32 | 0 x6] per point (SK=40), hn inline.
__global__ void pack3_kernel(const float* __restrict__ src, unsigned short* __restrict__ pk) {
    const int id = blockIdx.x;
    const int b = id & 7;
    const int m = (id >> 3) * 256 + threadIdx.x;
    us8 w0, w1;
    #pragma unroll
    for (int j = 0; j < 8; j++) { w0[j] = 0; w1[j] = 0; }
    unsigned short row[12];
    float s = 0.f;
    #pragma unroll
    for (int c = 0; c < 3; c++) {
        float v = src[(b * 3 + c) * NN + m];
        s += v * v;
        unsigned short h = bf16rn(v);
        unsigned short l = bf16rn(v - bf16up(h));
        row[c] = h; row[3 + c] = l; row[6 + c] = l; row[9 + c] = h;
    }
    #pragma unroll
    for (int j = 0; j < 8; j++) w0[j] = row[j];
    #pragma unroll
    for (int j = 0; j < 4; j++) w1[j] = row[8 + j];
    unsigned short* dst = pk + (size_t)(b * NN + m) * 40;
    us8 z;
    #pragma unroll
    for (int j = 0; j < 8; j++) z[j] = 0;
    unsigned int ub = __float_as_uint(0.5f * s);
    us8 zh = z;
    zh[0] = (unsigned short)(ub & 0xFFFFu);
    zh[1] = (unsigned short)(ub >> 16);
    *(us8*)(dst) = w0;
    *(us8*)(dst + 8) = w1;
    *(us8*)(dst + 16) = z;
    *(us8*)(dst + 24) = z;
    *(us8*)(dst + 32) = zh;
}

// ---------------- kNN via MFMA (bf16 hi/lo split, 4-term exact) ----------------
// ROUND-7 VERBATIM (best measured: 254us C=64). 64 q/block, 2 blocks/CU,
// double-buffered global_load_lds staging, hn in row pad, exact running tau,
// pool + tid<64 drain, 2 __syncthreads per chunk, XCD pinning.
template<int C>
__global__ __launch_bounds__(256) void knn_kernel(const float* __restrict__ src,
                                                  const unsigned short* __restrict__ pk,
                                                  int* __restrict__ idx) {
    constexpr int SK = (C == 3) ? 40 : (2 * C + 8);   // padded k-stride (shorts)
    constexpr int HNOFF = (C == 3) ? 32 : 2 * C;      // hn fp32 offset in row
    constexpr int UNITS = 8 * SK;                     // 16B units per 64-row chunk
    constexpr int PF = (UNITS + 255) / 256;
    constexpr int KKN = (C == 3) ? 1 : (C / 32);
    __shared__ __attribute__((aligned(16))) unsigned short cpack[2 * 64 * SK];
    __shared__ float pv[64 * 65];
    __shared__ unsigned short pidx[64 * 66];
    __shared__ float tau[64];
    __shared__ int cnt[64];
    __shared__ unsigned short qls[(C == 3) ? 64 * 40 : 2];

    const int bid = blockIdx.x;
    const int b = bid & 7;               // batch -> XCD (wgid % 8 round-robin)
    const int q0 = (bid >> 3) * 64;
    const int tid = threadIdx.x;
    const int lane = tid & 63;
    const int wv = tid >> 6;
    const int wr = (wv >> 1) * 32;      // wave q-offset in [0,64)
    const int wc = (wv & 1) * 32;       // wave m-offset in [0,64)
    const int fl = lane & 15;
    const int fq = lane >> 4;

    float tv[20]; int ti[20];
    #pragma unroll
    for (int k = 0; k < 20; k++) { tv[k] = -3.4e38f; ti[k] = 0; }

    // ---- A fragments (registers, once) ----
    bfrag qah[KKN][2], qal[KKN][2];
    if (C == 3) {
        for (int i = tid; i < 64 * 20; i += 256) {
            int r = i / 20, k = 12 + i % 20;
            qls[r * 40 + k] = 0;
        }
        if (tid < 64) {
            #pragma unroll
            for (int c = 0; c < 3; c++) {
                float v = src[(b * 3 + c) * NN + q0 + tid];
                unsigned short h = bf16rn(v);
                unsigned short l = bf16rn(v - bf16up(h));
                // A-pack: [h3 l3 h3 l3 | 0...] pairs with B-pack [h3 l3 l3 h3]
                qls[tid * 40 + c] = h;  qls[tid * 40 + 3 + c] = l;
                qls[tid * 40 + 6 + c] = h;  qls[tid * 40 + 9 + c] = l;
            }
        }
    } else {
        #pragma unroll
        for (int r2 = 0; r2 < 2; r2++) {
            const unsigned short* qr = pk + (size_t)(b * NN + q0 + wr + r2 * 16 + fl) * SK + fq * 8;
            #pragma unroll
            for (int kk = 0; kk < KKN; kk++) {
                qah[kk][r2] = *(const bfrag*)(qr + kk * 32);
                qal[kk][r2] = *(const bfrag*)(qr + C + kk * 32);
            }
        }
    }

    // ---- prologue: async-stage chunk 0 into buffer 0 ----
    {
        const unsigned short* p0 = pk + (size_t)(b * NN) * SK;
        #pragma unroll
        for (int r = 0; r < PF; r++) {
            int u0 = r * 256 + wv * 64;          // wave-uniform base unit
            if (u0 < UNITS)
                gl_lds16(p0 + (size_t)(u0 + lane) * 8, cpack + (size_t)u0 * 8);
        }
    }
    if (tid < 64) { tau[tid] = -3.4e38f; cnt[tid] = 0; }
    __syncthreads();    // drains vmcnt: chunk 0 resident

    bfrag qa3[2];
    if (C == 3) {
        #pragma unroll
        for (int r2 = 0; r2 < 2; r2++)
            qa3[r2] = *(const bfrag*)(&qls[(wr + r2 * 16 + fl) * 40 + fq * 8]);
    }

    int buf = 0;
    for (int ch = 0; ch < 64; ch++) {
        unsigned short* cur = cpack + buf * (64 * SK);
        // ---- Phase A: issue async stage of ch+1; MFMA + filter on cur ----
        if (ch + 1 < 64) {
            unsigned short* nxt = cpack + (buf ^ 1) * (64 * SK);
            const unsigned short* pn = pk + (size_t)(b * NN + (ch + 1) * 64) * SK;
            #pragma unroll
            for (int r = 0; r < PF; r++) {
                int u0 = r * 256 + wv * 64;
                if (u0 < UNITS)
                    gl_lds16(pn + (size_t)(u0 + lane) * 8, nxt + (size_t)u0 * 8);
            }
        }

        floatx4 acc[2][2];
        #pragma unroll
        for (int r2 = 0; r2 < 2; r2++)
            #pragma unroll
            for (int c2 = 0; c2 < 2; c2++)
                acc[r2][c2] = (floatx4)(0.f);

        if (C == 3) {
            #pragma unroll
            for (int c2 = 0; c2 < 2; c2++) {
                bfrag bm = *(const bfrag*)(&cur[(wc + c2 * 16 + fl) * SK + fq * 8]);
                #pragma unroll
                for (int r2 = 0; r2 < 2; r2++)
                    acc[r2][c2] = __builtin_amdgcn_mfma_f32_16x16x32_bf16(qa3[r2], bm, acc[r2][c2], 0, 0, 0);
            }
        } else {
            #pragma unroll
            for (int kk = 0; kk < KKN; kk++) {
                const int kb = kk * 32 + fq * 8;
                bfrag bh[2], bl[2];
                #pragma unroll
                for (int c2 = 0; c2 < 2; c2++) {
                    bh[c2] = *(const bfrag*)(&cur[(wc + c2 * 16 + fl) * SK + kb]);
                    bl[c2] = *(const bfrag*)(&cur[(wc + c2 * 16 + fl) * SK + C + kb]);
                }
                #pragma unroll
                for (int r2 = 0; r2 < 2; r2++)
                    #pragma unroll
                    for (int c2 = 0; c2 < 2; c2++) {
                        acc[r2][c2] = __builtin_amdgcn_mfma_f32_16x16x32_bf16(qah[kk][r2], bh[c2], acc[r2][c2], 0, 0, 0);
                        acc[r2][c2] = __builtin_amdgcn_mfma_f32_16x16x32_bf16(qah[kk][r2], bl[c2], acc[r2][c2], 0, 0, 0);
                        acc[r2][c2] = __builtin_amdgcn_mfma_f32_16x16x32_bf16(qal[kk][r2], bh[c2], acc[r2][c2], 0, 0, 0);
                        acc[r2][c2] = __builtin_amdgcn_mfma_f32_16x16x32_bf16(qal[kk][r2], bl[c2], acc[r2][c2], 0, 0, 0);
                    }
            }
        }

        // ---- filter: C-layout col=lane&15 (m), row=fq*4+reg (q); exact tau;
        //      hn read from the staged row pad in LDS ----
        {
            const int m0 = ch * 64;
            float hvv[2];
            #pragma unroll
            for (int c2 = 0; c2 < 2; c2++)
                hvv[c2] = *(const float*)(&cur[(wc + c2 * 16 + fl) * SK + HNOFF]);
            #pragma unroll
            for (int r2 = 0; r2 < 2; r2++) {
                const int qb = wr + r2 * 16 + fq * 4;
                float4 t4 = *(const float4*)(&tau[qb]);
                float ta[4] = { t4.x, t4.y, t4.z, t4.w };
                #pragma unroll
                for (int c2 = 0; c2 < 2; c2++) {
                    const float hv = hvv[c2];
                    const int mm = m0 + wc + c2 * 16 + fl;
                    #pragma unroll
                    for (int reg = 0; reg < 4; reg++) {
                        float s = acc[r2][c2][reg] - hv;
                        if (s > ta[reg]) {
                            int q = qb + reg;
                            int p = atomicAdd(&cnt[q], 1);   // <= 64 per chunk: fits
                            pv[q * 65 + p] = s;
                            pidx[q * 66 + p] = (unsigned short)mm;
                        }
                    }
                }
            }
        }
        __syncthreads();   // B1: pool complete; vmcnt(0) -> next chunk resident

        // ---- Phase B: drain (tid<64, lane-parallel over q); exact top-20 + tau ----
        if (tid < 64) {
            int n = cnt[tid];
            for (int t = 0; t < n; t++) {
                float v = pv[tid * 65 + t];
                if (v > tv[0]) {
                    tv[0] = v; ti[0] = (int)pidx[tid * 66 + t];
                    #pragma unroll
                    for (int j = 0; j < 19; j++) {
                        if (tv[j] > tv[j + 1]) {
                            float a = tv[j]; tv[j] = tv[j + 1]; tv[j + 1] = a;
                            int bi = ti[j]; ti[j] = ti[j + 1]; ti[j + 1] = bi;
                        }
                    }
                }
            }
            cnt[tid] = 0;
            tau[tid] = tv[0];
        }
        __syncthreads();   // B2: tau/cnt ready
        buf ^= 1;
    }

    if (tid < 64) {
        #pragma unroll
        for (int k = 0; k < 20; k++)
            idx[(b * NN + q0 + tid) * KK + k] = ti[k];   // order irrelevant downstream
    }
}

// ---------------- conv precompute: G = Wd*src, H = (Wc-Wd)*src ----------------
// XCD-pinned: b = blockIdx.x & 7.
template<int COUT>
__global__ void precompute_kernel(const float* __restrict__ src, int C,
                                  const float* __restrict__ w, int CIN, int wd_off, int wc_off,
                                  float* __restrict__ G, float* __restrict__ H) {
    constexpr int MY = 256 / COUT;
    extern __shared__ float lds[];
    float* wd = lds;
    float* wc = lds + C * COUT;
    const int id = blockIdx.x;
    const int b = id & 7;
    const int m_base = (id >> 3) * 64;
    const int tid = threadIdx.y * COUT + threadIdx.x;
    for (int i = tid; i < C * COUT; i += 256) {
        int c = i / COUT, o = i % COUT;
        float a  = w[o * CIN + wd_off + c];
        float cc = w[o * CIN + wc_off + c];
        wd[i] = a;
        wc[i] = cc - a;
    }
    __syncthreads();
    const int o = threadIdx.x;
    for (int it = 0; it < COUT / 4; it++) {
        int m = m_base + it * MY + threadIdx.y;
        float g = 0.f, h = 0.f;
        for (int c = 0; c < C; c++) {
            float s = src[(b * C + c) * NN + m];
            g += wd[c * COUT + o] * s;
            h += wc[c * COUT + o] * s;
        }
        int gi = (b * NN + m) * COUT + o;
        G[gi] = g;
        H[gi] = h;
    }
}

// conv2 fused dual-source precompute: SEPARATE GA (x, offs 0/3) and GB (x1m,
// offs 6/38) + combined H. One pass, one dispatch, no H read-modify-write.
__global__ void precompute2_kernel(const float* __restrict__ srcA, const float* __restrict__ srcB,
                                   const float* __restrict__ w,
                                   float* __restrict__ GA, float* __restrict__ GB,
                                   float* __restrict__ H) {
    constexpr int COUT = 64, CA = 3, CB = 32, CIN = 70;
    __shared__ float wdA[CA * COUT], wcA[CA * COUT], wdB[CB * COUT], wcB[CB * COUT];
    const int id = blockIdx.x;
    const int b = id & 7;
    const int m_base = (id >> 3) * 64;
    const int tid = threadIdx.y * COUT + threadIdx.x;
    for (int i = tid; i < CA * COUT; i += 256) {
        int c = i / COUT, o = i % COUT;
        float a = w[o * CIN + 0 + c], cc = w[o * CIN + 3 + c];
        wdA[i] = a; wcA[i] = cc - a;
    }
    for (int i = tid; i < CB * COUT; i += 256) {
        int c = i / COUT, o = i % COUT;
        float a = w[o * CIN + 6 + c], cc = w[o * CIN + 38 + c];
        wdB[i] = a; wcB[i] = cc - a;
    }
    __syncthreads();
    const int o = threadIdx.x;
    for (int it = 0; it < 16; it++) {
        int m = m_base + it * 4 + threadIdx.y;
        float ga = 0.f, gb = 0.f, h = 0.f;
        for (int c = 0; c < CA; c++) {
            float s = srcA[(b * CA + c) * NN + m];
            ga += wdA[c * COUT + o] * s;
            h  += wcA[c * COUT + o] * s;
        }
        for (int c = 0; c < CB; c++) {
            float s = srcB[(b * CB + c) * NN + m];
            gb += wdB[c * COUT + o] * s;
            h  += wcB[c * COUT + o] * s;
        }
        int gi = (b * NN + m) * COUT + o;
        GA[gi] = ga;
        GB[gi] = gb;
        H[gi] = h;
    }
}

// ---------------- conv stats + per-(b,n,o) selected extreme over k -------------
// sign(sc) = sign(g[o]) (rsqrt > 0): write single V = chosen extreme + h.
// XCD-pinned: b = blockIdx.x & 7 -> batch-b G-rows L2-resident.
template<int COUT, int GROUPS>
__global__ void conv_stats_kernel(const float* __restrict__ G1, const int* __restrict__ idx1,
                                  const float* __restrict__ G2, const int* __restrict__ idx2,
                                  const float* __restrict__ H, const float* __restrict__ gw,
                                  float* __restrict__ stats, float* __restrict__ V) {
    constexpr int NY = 256 / COUT;
    const int id = blockIdx.x;
    const int b = id & 7;
    const int o = threadIdx.x;
    const int n = (id >> 3) * NY + threadIdx.y;
    const int base = b * NN + n;
    const float h = H[base * COUT + o];
    float s1 = 0.f, s2 = 0.f;
    float gx = -3.4e38f, gn = 3.4e38f;
    #pragma unroll
    for (int k = 0; k < KK; k++) {
        int i1 = idx1[base * KK + k];
        float g = G1[(b * NN + i1) * COUT + o];
        if (GROUPS == 2) {
            int i2 = idx2[base * KK + k];
            g += G2[(b * NN + i2) * COUT + o];
        }
        float y = g + h;
        s1 += y;
        s2 += y * y;
        gx = fmaxf(gx, g);
        gn = fminf(gn, g);
    }
    V[base * COUT + o] = ((gw[o] >= 0.f) ? gx : gn) + h;

    __shared__ float ls[2 * COUT];
    if (threadIdx.y == 0) { ls[o] = 0.f; ls[COUT + o] = 0.f; }
    __syncthreads();
    atomicAdd(&ls[o], s1);
    atomicAdd(&ls[COUT + o], s2);
    __syncthreads();
    if (threadIdx.y == 0) {
        atomicAdd(&stats[o], ls[o]);
        atomicAdd(&stats[64 + o], ls[COUT + o]);
    }
}

// apply with fused finalize (for xd1/xd2): o block-uniform -> thread 0 computes
// sc/sh from raw sums, broadcast via LDS. XCD-pinned.
__global__ void apply_kernel(const float* __restrict__ V, const float* __restrict__ stats,
                             const float* __restrict__ g, const float* __restrict__ bb,
                             float* __restrict__ out, int cout, float invP) {
    const int id = blockIdx.x;
    const int b = id & 7;
    int e = (id >> 3) * 256 + threadIdx.x;
    int n = e & (NN - 1);
    int o = e >> 12;
    __shared__ float sc_s, sh_s;
    if (threadIdx.x == 0) {
        float mu  = stats[o] * invP;
        float var = stats[64 + o] * invP - mu * mu;
        float sc  = g[o] * rsqrtf(var + EPSV);
        sc_s = sc;
        sh_s = bb[o] - mu * sc;
    }
    __syncthreads();
    float v = V[(b * NN + n) * cout + o];
    out[(b * cout + o) * NN + n] = lrelu(sc_s * v + sh_s);
}

// ---------------- FUSED apply + pack (for x1m, x2m) ----------------
// Reads V, applies BN affine + lrelu (finalize fused), writes BOTH the fp32
// tensor xm AND the bf16 hi/lo packed rows + hn pad for the next kNN.
// Pad region [2C+2,2C+8) of each pk row is never read -> left unwritten.
// XCD-pinned: b = blockIdx.x & 7; block covers 64 points x COUT channels.
template<int COUT>
__global__ void applypack_kernel(const float* __restrict__ V, const float* __restrict__ stats,
                                 const float* __restrict__ g, const float* __restrict__ bb,
                                 float* __restrict__ xm, unsigned short* __restrict__ pk,
                                 float invP) {
    constexpr int SK = 2 * COUT + 8;
    constexpr int Q = COUT / 4;          // channels per thread (4 threads/point)
    __shared__ float sc_s[COUT], sh_s[COUT], hnacc[64];
    const int id = blockIdx.x;
    const int b = id & 7;
    const int m0 = (id >> 3) * 64;
    const int tid = threadIdx.x;
    if (tid < COUT) {
        float mu  = stats[tid] * invP;
        float var = stats[64 + tid] * invP - mu * mu;
        float sc  = g[tid] * rsqrtf(var + EPSV);
        sc_s[tid] = sc;
        sh_s[tid] = bb[tid] - mu * sc;
    }
    if (tid < 64) hnacc[tid] = 0.f;
    __syncthreads();
    const int n = tid & 63;
    const int oc = (tid >> 6) * Q;
    const float* vp = V + ((size_t)(b * NN + m0 + n) * COUT + oc);
    float y[Q];
    float s = 0.f;
    #pragma unroll
    for (int j = 0; j < Q; j++) {
        float yy = lrelu(sc_s[oc + j] * vp[j] + sh_s[oc + j]);
        y[j] = yy;
        s += yy * yy;
        xm[(b * COUT + oc + j) * NN + m0 + n] = yy;
    }
    atomicAdd(&hnacc[n], s);
    unsigned short* pr = pk + (size_t)(b * NN + m0 + n) * SK;
    #pragma unroll
    for (int j4 = 0; j4 < Q / 4; j4++) {
        us4 hv, lv;
        #pragma unroll
        for (int j = 0; j < 4; j++) {
            float yy = y[j4 * 4 + j];
            unsigned short h = bf16rn(yy);
            hv[j] = h;
            lv[j] = bf16rn(yy - bf16up(h));
        }
        *(us4*)(pr + oc + j4 * 4) = hv;
        *(us4*)(pr + COUT + oc + j4 * 4) = lv;
    }
    __syncthreads();
    if (tid < 64)
        *(unsigned int*)(pk + (size_t)(b * NN + m0 + tid) * SK + 2 * COUT) =
            __float_as_uint(0.5f * hnacc[tid]);
}

__global__ void mean_kernel(const float* __restrict__ xd1, const float* __restrict__ xd2,
                            float* __restrict__ hsum) {
    __shared__ float bins[128];
    const int tid = threadIdx.x;
    if (tid < 128) bins[tid] = 0.f;
    __syncthreads();
    const int half = BB * 64 * NN;
    const int stride = gridDim.x * 256;
    for (int e = blockIdx.x * 256 + tid; e < half; e += stride)
        atomicAdd(&bins[e & 127], xd1[e]);
    for (int e = blockIdx.x * 256 + tid; e < half; e += stride)
        atomicAdd(&bins[e & 127], xd2[e]);
    __syncthreads();
    if (tid < 128) atomicAdd(&hsum[tid], bins[tid]);
}

__global__ void head_kernel(const float* __restrict__ hsum,
                            const float* __restrict__ W2d, const float* __restrict__ b2d,
                            const float* __restrict__ W3d, const float* __restrict__ b3d,
                            const float* __restrict__ W4d, const float* __restrict__ b4d,
                            float* __restrict__ out) {
    __shared__ float h[128], t1[128], t2[64];
    const int t = threadIdx.x;
    h[t] = hsum[t] * (1.f / 32768.f);
    __syncthreads();
    float a = b2d[t];
    for (int j = 0; j < 128; j++) a += W2d[t * 128 + j] * h[j];
    t1[t] = lrelu(a);
    __syncthreads();
    if (t < 64) {
        float a2 = b3d[t];
        for (int j = 0; j < 128; j++) a2 += W3d[t * 128 + j] * t1[j];
        t2[t] = lrelu(a2);
    }
    __syncthreads();
    if (t < 11) {
        float a3 = b4d[t];
        for (int j = 0; j < 64; j++) a3 += W4d[t * 64 + j] * t2[j];
        out[t] = lrelu(a3);
    }
}

extern "C" void kernel_launch(void* const* d_in, const int* in_sizes, int n_in,
                              void* d_out, int out_size, void* d_ws, size_t ws_size,
                              hipStream_t stream) {
    const float* x   = (const float*)d_in[0];
    const float* w1  = (const float*)d_in[1];
    const float* g1  = (const float*)d_in[2];
    const float* b1  = (const float*)d_in[3];
    const float* w2  = (const float*)d_in[4];
    const float* g2  = (const float*)d_in[5];
    const float* b2  = (const float*)d_in[6];
    const float* wd1 = (const float*)d_in[7];
    const float* gd1 = (const float*)d_in[8];
    const float* bd1 = (const float*)d_in[9];
    const float* wd2 = (const float*)d_in[10];
    const float* gd2 = (const float*)d_in[11];
    const float* bd2 = (const float*)d_in[12];
    const float* W2d = (const float*)d_in[13];
    const float* b2d = (const float*)d_in[14];
    const float* W3d = (const float*)d_in[15];
    const float* b3d = (const float*)d_in[16];
    const float* W4d = (const float*)d_in[17];
    const float* b4d = (const float*)d_in[18];
    float* out = (float*)d_out;

    char* ws = (char*)d_ws;
    size_t off = 0;
    auto alloc = [&](size_t bytes) { char* p = ws + off; off += (bytes + 255) & ~size_t(255); return p; };
    int*   idx1  = (int*)  alloc(BB * NN * KK * 4);
    int*   idx2  = (int*)  alloc(BB * NN * KK * 4);
    int*   idx3  = (int*)  alloc(BB * NN * KK * 4);
    float* x1m   = (float*)alloc(BB * 32 * NN * 4);
    float* x2m   = (float*)alloc(BB * 64 * NN * 4);
    float* xd1   = (float*)alloc(BB * 64 * NN * 4);
    float* xd2   = (float*)alloc(BB * 64 * NN * 4);
    float* G1    = (float*)alloc((size_t)BB * NN * 64 * 4);   // 8.39MB, contiguous with G2
    float* G2    = (float*)alloc((size_t)BB * NN * 64 * 4);
    float* H     = (float*)alloc((size_t)BB * NN * 64 * 4);
    float* Vbuf  = (float*)alloc((size_t)BB * NN * 64 * 4);
    float* stats = (float*)alloc(4 * 256 * 4);    // 4 slabs: conv1/conv2/convd1/convd2
    float* hsum  = (float*)alloc(128 * 4);

    float* st0 = stats;
    float* st1 = stats + 256;
    float* st2 = stats + 512;
    float* st3 = stats + 768;

    // pk placements (all dead-buffer reuse, verified under stream order):
    //  pk3  (2.6MB) -> Vbuf       (Vbuf first written by conv1 stats, after knn3)
    //  pk32 (4.7MB) -> G2         (G2 next written by pre2, after knn32)
    //  pk64 (8.9MB) -> G1 + 0.5MB spill into G2 head (both dead after conv2
    //                  stats; knn64 runs before convd1's precompute rewrites G2)
    unsigned short* pk3  = (unsigned short*)Vbuf;
    unsigned short* pk32 = (unsigned short*)G2;
    unsigned short* pk64 = (unsigned short*)G1;

    const float invP = 1.f / (float)(BB * NN * KK);
    const dim3 knn_grid(NN / 64 * BB);     // 1D: b = id & 7 (XCD pinning)
    const dim3 pre_grid(NN / 64 * BB);

    // one upfront zero: 4 stats slabs (1024 floats) + hsum (128), contiguous.
    zero_kernel<<<5, 256, 0, stream>>>(stats, 1024 + 128);

    // --- kNN on x (C=3) ---
    pack3_kernel<<<NN / 256 * BB, 256, 0, stream>>>(x, pk3);
    knn_kernel<3><<<knn_grid, 256, 0, stream>>>(x, pk3, idx1);

    // --- conv1: Cout=32, group (x, idx1, C=3), w1 CIN=6 ---
    precompute_kernel<32><<<pre_grid, dim3(32, 8), 2 * 3 * 32 * 4, stream>>>(
        x, 3, w1, 6, 0, 3, G1, H);
    conv_stats_kernel<32, 1><<<NN / 8 * BB, dim3(32, 8), 0, stream>>>(
        G1, idx1, nullptr, nullptr, H, g1, st0, Vbuf);
    applypack_kernel<32><<<pre_grid, 256, 0, stream>>>(Vbuf, st0, g1, b1, x1m, pk32, invP);

    // --- kNN on x1_max (C=32) ---
    knn_kernel<32><<<knn_grid, 256, 0, stream>>>(x1m, pk32, idx2);

    // --- conv2: Cout=64, groups (x, idx1, 3) + (x1m, idx2, 32), w2 CIN=70 ---
    precompute2_kernel<<<pre_grid, dim3(64, 4), 0, stream>>>(x, x1m, w2, G1, G2, H);
    conv_stats_kernel<64, 2><<<NN / 4 * BB, dim3(64, 4), 0, stream>>>(
        G1, idx1, G2, idx2, H, g2, st1, Vbuf);
    applypack_kernel<64><<<pre_grid, 256, 0, stream>>>(Vbuf, st1, g2, b2, x2m, pk64, invP);

    // --- kNN on x2_max (C=64): moved before convd1 (convd1's precompute would
    //     clobber pk64's spill into G2) ---
    knn_kernel<64><<<knn_grid, 256, 0, stream>>>(x2m, pk64, idx3);

    // --- convd1: Cout=64, group (x1m, idx2, 32), wd1 CIN=64 ---
    precompute_kernel<64><<<pre_grid, dim3(64, 4), 2 * 32 * 64 * 4, stream>>>(
        x1m, 32, wd1, 64, 0, 32, G2, H);
    conv_stats_kernel<64, 1><<<NN / 4 * BB, dim3(64, 4), 0, stream>>>(
        G2, idx2, nullptr, nullptr, H, gd1, st2, Vbuf);
    apply_kernel<<<64 * NN / 256 * BB, 256, 0, stream>>>(Vbuf, st2, gd1, bd1, xd1, 64, invP);

    // --- convd2: Cout=64, group (x2m, idx3, 64), wd2 CIN=128 ---
    precompute_kernel<64><<<pre_grid, dim3(64, 4), 2 * 64 * 64 * 4, stream>>>(
        x2m, 64, wd2, 128, 0, 64, G1, H);
    conv_stats_kernel<64, 1><<<NN / 4 * BB, dim3(64, 4), 0, stream>>>(
        G1, idx3, nullptr, nullptr, H, gd2, st3, Vbuf);
    apply_kernel<<<64 * NN / 256 * BB, 256, 0, stream>>>(Vbuf, st3, gd2, bd2, xd2, 64, invP);

    // --- global mean + MLP head ---
    mean_kernel<<<1024, 256, 0, stream>>>(xd1, xd2, hsum);
    head_kernel<<<1, 128, 0, stream>>>(hsum, W2d, b2d, W3d, b3d, W4d, b4d, out);
}

// Round 17
// 1606.709 us; speedup vs baseline: 1.1342x; 1.0123x over previous
//
#include <hip/hip_runtime.h>

#define BB 8
#define NN 4096
#define KK 20
constexpr float EPSV = 1e-5f;
constexpr float SLOPE = 0.2f;

typedef __bf16 bfrag __attribute__((ext_vector_type(8)));
typedef float floatx4 __attribute__((ext_vector_type(4)));
typedef unsigned short us4 __attribute__((ext_vector_type(4)));
typedef unsigned short us8 __attribute__((ext_vector_type(8)));

__device__ __forceinline__ float lrelu(float v) { return v >= 0.f ? v : SLOPE * v; }

__device__ __forceinline__ unsigned short bf16rn(float f) {
    unsigned int u = __float_as_uint(f);
    return (unsigned short)((u + 0x7FFFu + ((u >> 16) & 1u)) >> 16);
}
__device__ __forceinline__ float bf16up(unsigned short h) {
    return __uint_as_float(((unsigned int)h) << 16);
}

// async global->LDS DMA, 16B per lane; lds dest must be wave-uniform base.
__device__ __forceinline__ void gl_lds16(const unsigned short* g, unsigned short* l) {
    __builtin_amdgcn_global_load_lds((const __attribute__((address_space(1))) void*)g,
                                     (__attribute__((address_space(3))) void*)l, 16, 0, 0);
}

__global__ void zero_kernel(float* p, int n) {
    int i = blockIdx.x * 256 + threadIdx.x;
    if (i < n) p[i] = 0.f;
}

// C=3 B-pack: [h3 l3 l3 h3 | 0 x20 | hn fp32 | 0 x6] per point (SK=40), hn inline.
__global__ void pack3_kernel(const float* __restrict__ src, unsigned short* __restrict__ pk) {
    const int id = blockIdx.x;
    const int b = id & 7;
    const int m = (id >> 3) * 256 + threadIdx.x;
    us8 w0, w1;
    #pragma unroll
    for (int j = 0; j < 8; j++) { w0[j] = 0; w1[j] = 0; }
    unsigned short row[12];
    float s = 0.f;
    #pragma unroll
    for (int c = 0; c < 3; c++) {
        float v = src[(b * 3 + c) * NN + m];
        s += v * v;
        unsigned short h = bf16rn(v);
        unsigned short l = bf16rn(v - bf16up(h));
        row[c] = h; row[3 + c] = l; row[6 + c] = l; row[9 + c] = h;
    }
    #pragma unroll
    for (int j = 0; j < 8; j++) w0[j] = row[j];
    #pragma unroll
    for (int j = 0; j < 4; j++) w1[j] = row[8 + j];
    unsigned short* dst = pk + (size_t)(b * NN + m) * 40;
    us8 z;
    #pragma unroll
    for (int j = 0; j < 8; j++) z[j] = 0;
    unsigned int ub = __float_as_uint(0.5f * s);
    us8 zh = z;
    zh[0] = (unsigned short)(ub & 0xFFFFu);
    zh[1] = (unsigned short)(ub >> 16);
    *(us8*)(dst) = w0;
    *(us8*)(dst + 8) = w1;
    *(us8*)(dst + 16) = z;
    *(us8*)(dst + 24) = z;
    *(us8*)(dst + 32) = zh;
}

// ---------------- kNN via MFMA (bf16 hi/lo split, 4-term exact) ----------------
// ROUND-7 VERBATIM (best measured: 254us C=64). 64 q/block, 2 blocks/CU,
// double-buffered global_load_lds staging, hn in row pad, exact running tau,
// pool + tid<64 drain, 2 __syncthreads per chunk, XCD pinning.
template<int C>
__global__ __launch_bounds__(256) void knn_kernel(const float* __restrict__ src,
                                                  const unsigned short* __restrict__ pk,
                                                  int* __restrict__ idx) {
    constexpr int SK = (C == 3) ? 40 : (2 * C + 8);   // padded k-stride (shorts)
    constexpr int HNOFF = (C == 3) ? 32 : 2 * C;      // hn fp32 offset in row
    constexpr int UNITS = 8 * SK;                     // 16B units per 64-row chunk
    constexpr int PF = (UNITS + 255) / 256;
    constexpr int KKN = (C == 3) ? 1 : (C / 32);
    __shared__ __attribute__((aligned(16))) unsigned short cpack[2 * 64 * SK];
    __shared__ float pv[64 * 65];
    __shared__ unsigned short pidx[64 * 66];
    __shared__ float tau[64];
    __shared__ int cnt[64];
    __shared__ unsigned short qls[(C == 3) ? 64 * 40 : 2];

    const int bid = blockIdx.x;
    const int b = bid & 7;               // batch -> XCD (wgid % 8 round-robin)
    const int q0 = (bid >> 3) * 64;
    const int tid = threadIdx.x;
    const int lane = tid & 63;
    const int wv = tid >> 6;
    const int wr = (wv >> 1) * 32;      // wave q-offset in [0,64)
    const int wc = (wv & 1) * 32;       // wave m-offset in [0,64)
    const int fl = lane & 15;
    const int fq = lane >> 4;

    float tv[20]; int ti[20];
    #pragma unroll
    for (int k = 0; k < 20; k++) { tv[k] = -3.4e38f; ti[k] = 0; }

    // ---- A fragments (registers, once) ----
    bfrag qah[KKN][2], qal[KKN][2];
    if (C == 3) {
        for (int i = tid; i < 64 * 20; i += 256) {
            int r = i / 20, k = 12 + i % 20;
            qls[r * 40 + k] = 0;
        }
        if (tid < 64) {
            #pragma unroll
            for (int c = 0; c < 3; c++) {
                float v = src[(b * 3 + c) * NN + q0 + tid];
                unsigned short h = bf16rn(v);
                unsigned short l = bf16rn(v - bf16up(h));
                // A-pack: [h3 l3 h3 l3 | 0...] pairs with B-pack [h3 l3 l3 h3]
                qls[tid * 40 + c] = h;  qls[tid * 40 + 3 + c] = l;
                qls[tid * 40 + 6 + c] = h;  qls[tid * 40 + 9 + c] = l;
            }
        }
    } else {
        #pragma unroll
        for (int r2 = 0; r2 < 2; r2++) {
            const unsigned short* qr = pk + (size_t)(b * NN + q0 + wr + r2 * 16 + fl) * SK + fq * 8;
            #pragma unroll
            for (int kk = 0; kk < KKN; kk++) {
                qah[kk][r2] = *(const bfrag*)(qr + kk * 32);
                qal[kk][r2] = *(const bfrag*)(qr + C + kk * 32);
            }
        }
    }

    // ---- prologue: async-stage chunk 0 into buffer 0 ----
    {
        const unsigned short* p0 = pk + (size_t)(b * NN) * SK;
        #pragma unroll
        for (int r = 0; r < PF; r++) {
            int u0 = r * 256 + wv * 64;          // wave-uniform base unit
            if (u0 < UNITS)
                gl_lds16(p0 + (size_t)(u0 + lane) * 8, cpack + (size_t)u0 * 8);
        }
    }
    if (tid < 64) { tau[tid] = -3.4e38f; cnt[tid] = 0; }
    __syncthreads();    // drains vmcnt: chunk 0 resident

    bfrag qa3[2];
    if (C == 3) {
        #pragma unroll
        for (int r2 = 0; r2 < 2; r2++)
            qa3[r2] = *(const bfrag*)(&qls[(wr + r2 * 16 + fl) * 40 + fq * 8]);
    }

    int buf = 0;
    for (int ch = 0; ch < 64; ch++) {
        unsigned short* cur = cpack + buf * (64 * SK);
        // ---- Phase A: issue async stage of ch+1; MFMA + filter on cur ----
        if (ch + 1 < 64) {
            unsigned short* nxt = cpack + (buf ^ 1) * (64 * SK);
            const unsigned short* pn = pk + (size_t)(b * NN + (ch + 1) * 64) * SK;
            #pragma unroll
            for (int r = 0; r < PF; r++) {
                int u0 = r * 256 + wv * 64;
                if (u0 < UNITS)
                    gl_lds16(pn + (size_t)(u0 + lane) * 8, nxt + (size_t)u0 * 8);
            }
        }

        floatx4 acc[2][2];
        #pragma unroll
        for (int r2 = 0; r2 < 2; r2++)
            #pragma unroll
            for (int c2 = 0; c2 < 2; c2++)
                acc[r2][c2] = (floatx4)(0.f);

        if (C == 3) {
            #pragma unroll
            for (int c2 = 0; c2 < 2; c2++) {
                bfrag bm = *(const bfrag*)(&cur[(wc + c2 * 16 + fl) * SK + fq * 8]);
                #pragma unroll
                for (int r2 = 0; r2 < 2; r2++)
                    acc[r2][c2] = __builtin_amdgcn_mfma_f32_16x16x32_bf16(qa3[r2], bm, acc[r2][c2], 0, 0, 0);
            }
        } else {
            #pragma unroll
            for (int kk = 0; kk < KKN; kk++) {
                const int kb = kk * 32 + fq * 8;
                bfrag bh[2], bl[2];
                #pragma unroll
                for (int c2 = 0; c2 < 2; c2++) {
                    bh[c2] = *(const bfrag*)(&cur[(wc + c2 * 16 + fl) * SK + kb]);
                    bl[c2] = *(const bfrag*)(&cur[(wc + c2 * 16 + fl) * SK + C + kb]);
                }
                #pragma unroll
                for (int r2 = 0; r2 < 2; r2++)
                    #pragma unroll
                    for (int c2 = 0; c2 < 2; c2++) {
                        acc[r2][c2] = __builtin_amdgcn_mfma_f32_16x16x32_bf16(qah[kk][r2], bh[c2], acc[r2][c2], 0, 0, 0);
                        acc[r2][c2] = __builtin_amdgcn_mfma_f32_16x16x32_bf16(qah[kk][r2], bl[c2], acc[r2][c2], 0, 0, 0);
                        acc[r2][c2] = __builtin_amdgcn_mfma_f32_16x16x32_bf16(qal[kk][r2], bh[c2], acc[r2][c2], 0, 0, 0);
                        acc[r2][c2] = __builtin_amdgcn_mfma_f32_16x16x32_bf16(qal[kk][r2], bl[c2], acc[r2][c2], 0, 0, 0);
                    }
            }
        }

        // ---- filter: C-layout col=lane&15 (m), row=fq*4+reg (q); exact tau;
        //      hn read from the staged row pad in LDS ----
        {
            const int m0 = ch * 64;
            float hvv[2];
            #pragma unroll
            for (int c2 = 0; c2 < 2; c2++)
                hvv[c2] = *(const float*)(&cur[(wc + c2 * 16 + fl) * SK + HNOFF]);
            #pragma unroll
            for (int r2 = 0; r2 < 2; r2++) {
                const int qb = wr + r2 * 16 + fq * 4;
                float4 t4 = *(const float4*)(&tau[qb]);
                float ta[4] = { t4.x, t4.y, t4.z, t4.w };
                #pragma unroll
                for (int c2 = 0; c2 < 2; c2++) {
                    const float hv = hvv[c2];
                    const int mm = m0 + wc + c2 * 16 + fl;
                    #pragma unroll
                    for (int reg = 0; reg < 4; reg++) {
                        float s = acc[r2][c2][reg] - hv;
                        if (s > ta[reg]) {
                            int q = qb + reg;
                            int p = atomicAdd(&cnt[q], 1);   // <= 64 per chunk: fits
                            pv[q * 65 + p] = s;
                            pidx[q * 66 + p] = (unsigned short)mm;
                        }
                    }
                }
            }
        }
        __syncthreads();   // B1: pool complete; vmcnt(0) -> next chunk resident

        // ---- Phase B: drain (tid<64, lane-parallel over q); exact top-20 + tau ----
        if (tid < 64) {
            int n = cnt[tid];
            for (int t = 0; t < n; t++) {
                float v = pv[tid * 65 + t];
                if (v > tv[0]) {
                    tv[0] = v; ti[0] = (int)pidx[tid * 66 + t];
                    #pragma unroll
                    for (int j = 0; j < 19; j++) {
                        if (tv[j] > tv[j + 1]) {
                            float a = tv[j]; tv[j] = tv[j + 1]; tv[j + 1] = a;
                            int bi = ti[j]; ti[j] = ti[j + 1]; ti[j + 1] = bi;
                        }
                    }
                }
            }
            cnt[tid] = 0;
            tau[tid] = tv[0];
        }
        __syncthreads();   // B2: tau/cnt ready
        buf ^= 1;
    }

    if (tid < 64) {
        #pragma unroll
        for (int k = 0; k < 20; k++)
            idx[(b * NN + q0 + tid) * KK + k] = ti[k];   // order irrelevant downstream
    }
}

// ---------------- conv precompute: G = Wd*src, H = (Wc-Wd)*src ----------------
// XCD-pinned: b = blockIdx.x & 7.
template<int COUT>
__global__ void precompute_kernel(const float* __restrict__ src, int C,
                                  const float* __restrict__ w, int CIN, int wd_off, int wc_off,
                                  float* __restrict__ G, float* __restrict__ H) {
    constexpr int MY = 256 / COUT;
    extern __shared__ float lds[];
    float* wd = lds;
    float* wc = lds + C * COUT;
    const int id = blockIdx.x;
    const int b = id & 7;
    const int m_base = (id >> 3) * 64;
    const int tid = threadIdx.y * COUT + threadIdx.x;
    for (int i = tid; i < C * COUT; i += 256) {
        int c = i / COUT, o = i % COUT;
        float a  = w[o * CIN + wd_off + c];
        float cc = w[o * CIN + wc_off + c];
        wd[i] = a;
        wc[i] = cc - a;
    }
    __syncthreads();
    const int o = threadIdx.x;
    for (int it = 0; it < COUT / 4; it++) {
        int m = m_base + it * MY + threadIdx.y;
        float g = 0.f, h = 0.f;
        for (int c = 0; c < C; c++) {
            float s = src[(b * C + c) * NN + m];
            g += wd[c * COUT + o] * s;
            h += wc[c * COUT + o] * s;
        }
        int gi = (b * NN + m) * COUT + o;
        G[gi] = g;
        H[gi] = h;
    }
}

// conv2 fused dual-source precompute: SEPARATE GA (x, offs 0/3) and GB (x1m,
// offs 6/38) + combined H. One pass, one dispatch, no H read-modify-write.
__global__ void precompute2_kernel(const float* __restrict__ srcA, const float* __restrict__ srcB,
                                   const float* __restrict__ w,
                                   float* __restrict__ GA, float* __restrict__ GB,
                                   float* __restrict__ H) {
    constexpr int COUT = 64, CA = 3, CB = 32, CIN = 70;
    __shared__ float wdA[CA * COUT], wcA[CA * COUT], wdB[CB * COUT], wcB[CB * COUT];
    const int id = blockIdx.x;
    const int b = id & 7;
    const int m_base = (id >> 3) * 64;
    const int tid = threadIdx.y * COUT + threadIdx.x;
    for (int i = tid; i < CA * COUT; i += 256) {
        int c = i / COUT, o = i % COUT;
        float a = w[o * CIN + 0 + c], cc = w[o * CIN + 3 + c];
        wdA[i] = a; wcA[i] = cc - a;
    }
    for (int i = tid; i < CB * COUT; i += 256) {
        int c = i / COUT, o = i % COUT;
        float a = w[o * CIN + 6 + c], cc = w[o * CIN + 38 + c];
        wdB[i] = a; wcB[i] = cc - a;
    }
    __syncthreads();
    const int o = threadIdx.x;
    for (int it = 0; it < 16; it++) {
        int m = m_base + it * 4 + threadIdx.y;
        float ga = 0.f, gb = 0.f, h = 0.f;
        for (int c = 0; c < CA; c++) {
            float s = srcA[(b * CA + c) * NN + m];
            ga += wdA[c * COUT + o] * s;
            h  += wcA[c * COUT + o] * s;
        }
        for (int c = 0; c < CB; c++) {
            float s = srcB[(b * CB + c) * NN + m];
            gb += wdB[c * COUT + o] * s;
            h  += wcB[c * COUT + o] * s;
        }
        int gi = (b * NN + m) * COUT + o;
        GA[gi] = ga;
        GB[gi] = gb;
        H[gi] = h;
    }
}

// ---------------- conv stats + per-(b,n,o) selected extreme over k -------------
// sign(sc) = sign(g[o]) (rsqrt > 0): write single V = chosen extreme + h.
// XCD-pinned: b = blockIdx.x & 7 -> batch-b G-rows L2-resident.
template<int COUT, int GROUPS>
__global__ void conv_stats_kernel(const float* __restrict__ G1, const int* __restrict__ idx1,
                                  const float* __restrict__ G2, const int* __restrict__ idx2,
                                  const float* __restrict__ H, const float* __restrict__ gw,
                                  float* __restrict__ stats, float* __restrict__ V) {
    constexpr int NY = 256 / COUT;
    const int id = blockIdx.x;
    const int b = id & 7;
    const int o = threadIdx.x;
    const int n = (id >> 3) * NY + threadIdx.y;
    const int base = b * NN + n;
    const float h = H[base * COUT + o];
    float s1 = 0.f, s2 = 0.f;
    float gx = -3.4e38f, gn = 3.4e38f;
    #pragma unroll
    for (int k = 0; k < KK; k++) {
        int i1 = idx1[base * KK + k];
        float g = G1[(b * NN + i1) * COUT + o];
        if (GROUPS == 2) {
            int i2 = idx2[base * KK + k];
            g += G2[(b * NN + i2) * COUT + o];
        }
        float y = g + h;
        s1 += y;
        s2 += y * y;
        gx = fmaxf(gx, g);
        gn = fminf(gn, g);
    }
    V[base * COUT + o] = ((gw[o] >= 0.f) ? gx : gn) + h;

    __shared__ float ls[2 * COUT];
    if (threadIdx.y == 0) { ls[o] = 0.f; ls[COUT + o] = 0.f; }
    __syncthreads();
    atomicAdd(&ls[o], s1);
    atomicAdd(&ls[COUT + o], s2);
    __syncthreads();
    if (threadIdx.y == 0) {
        atomicAdd(&stats[o], ls[o]);
        atomicAdd(&stats[64 + o], ls[COUT + o]);
    }
}

// apply with fused finalize + LDS transpose (for xd1/xd2, COUT=64):
// phase 1 reads V o-fast (wave = one n, lanes = channels -> coalesced 256B),
// phase 2 writes out n-fast (coalesced). Same math as before. XCD-pinned.
__global__ void apply_t_kernel(const float* __restrict__ V, const float* __restrict__ stats,
                               const float* __restrict__ g, const float* __restrict__ bb,
                               float* __restrict__ out, float invP) {
    __shared__ float sc_s[64], sh_s[64];
    __shared__ float tr[64 * 65];
    const int id = blockIdx.x;
    const int b = id & 7;
    const int m0 = (id >> 3) * 64;
    const int tid = threadIdx.x;
    if (tid < 64) {
        float mu  = stats[tid] * invP;
        float var = stats[64 + tid] * invP - mu * mu;
        float sc  = g[tid] * rsqrtf(var + EPSV);
        sc_s[tid] = sc;
        sh_s[tid] = bb[tid] - mu * sc;
    }
    const int o = tid & 63;
    const int grp = tid >> 6;            // 4 rows per pass
    #pragma unroll
    for (int it = 0; it < 16; it++) {
        int n = it * 4 + grp;
        tr[n * 65 + o] = V[((size_t)(b * NN + m0 + n)) * 64 + o];
    }
    __syncthreads();
    const int n2 = tid & 63;
    #pragma unroll
    for (int it = 0; it < 16; it++) {
        int o2 = it * 4 + grp;
        float y = lrelu(sc_s[o2] * tr[n2 * 65 + o2] + sh_s[o2]);
        out[((size_t)(b * 64 + o2)) * NN + m0 + n2] = y;
    }
}

// ---------------- FUSED apply + pack (for x1m, x2m) ----------------
// Reads V, applies BN affine + lrelu (finalize fused), writes BOTH the fp32
// tensor xm AND the bf16 hi/lo packed rows + hn pad for the next kNN.
// Pad region [2C+2,2C+8) of each pk row is never read -> left unwritten.
// XCD-pinned: b = blockIdx.x & 7; block covers 64 points x COUT channels.
template<int COUT>
__global__ void applypack_kernel(const float* __restrict__ V, const float* __restrict__ stats,
                                 const float* __restrict__ g, const float* __restrict__ bb,
                                 float* __restrict__ xm, unsigned short* __restrict__ pk,
                                 float invP) {
    constexpr int SK = 2 * COUT + 8;
    constexpr int Q = COUT / 4;          // channels per thread (4 threads/point)
    __shared__ float sc_s[COUT], sh_s[COUT], hnacc[64];
    const int id = blockIdx.x;
    const int b = id & 7;
    const int m0 = (id >> 3) * 64;
    const int tid = threadIdx.x;
    if (tid < COUT) {
        float mu  = stats[tid] * invP;
        float var = stats[64 + tid] * invP - mu * mu;
        float sc  = g[tid] * rsqrtf(var + EPSV);
        sc_s[tid] = sc;
        sh_s[tid] = bb[tid] - mu * sc;
    }
    if (tid < 64) hnacc[tid] = 0.f;
    __syncthreads();
    const int n = tid & 63;
    const int oc = (tid >> 6) * Q;
    const float* vp = V + ((size_t)(b * NN + m0 + n) * COUT + oc);
    float y[Q];
    float s = 0.f;
    #pragma unroll
    for (int j = 0; j < Q; j++) {
        float yy = lrelu(sc_s[oc + j] * vp[j] + sh_s[oc + j]);
        y[j] = yy;
        s += yy * yy;
        xm[(b * COUT + oc + j) * NN + m0 + n] = yy;
    }
    atomicAdd(&hnacc[n], s);
    unsigned short* pr = pk + (size_t)(b * NN + m0 + n) * SK;
    #pragma unroll
    for (int j4 = 0; j4 < Q / 4; j4++) {
        us4 hv, lv;
        #pragma unroll
        for (int j = 0; j < 4; j++) {
            float yy = y[j4 * 4 + j];
            unsigned short h = bf16rn(yy);
            hv[j] = h;
            lv[j] = bf16rn(yy - bf16up(h));
        }
        *(us4*)(pr + oc + j4 * 4) = hv;
        *(us4*)(pr + COUT + oc + j4 * 4) = lv;
    }
    __syncthreads();
    if (tid < 64)
        *(unsigned int*)(pk + (size_t)(b * NN + m0 + tid) * SK + 2 * COUT) =
            __float_as_uint(0.5f * hnacc[tid]);
}

// mean over both halves: each thread's grid-stride elements all share one bin
// (stride % 128 == 0), so accumulate privately and do ONE LDS atomic at end.
__global__ void mean_kernel(const float* __restrict__ xd1, const float* __restrict__ xd2,
                            float* __restrict__ hsum) {
    __shared__ float bins[128];
    const int tid = threadIdx.x;
    if (tid < 128) bins[tid] = 0.f;
    __syncthreads();
    const int half = BB * 64 * NN;
    const int stride = gridDim.x * 256;
    float acc = 0.f;
    for (int e = blockIdx.x * 256 + tid; e < half; e += stride)
        acc += xd1[e] + xd2[e];
    atomicAdd(&bins[tid & 127], acc);
    __syncthreads();
    if (tid < 128) atomicAdd(&hsum[tid], bins[tid]);
}

__global__ void head_kernel(const float* __restrict__ hsum,
                            const float* __restrict__ W2d, const float* __restrict__ b2d,
                            const float* __restrict__ W3d, const float* __restrict__ b3d,
                            const float* __restrict__ W4d, const float* __restrict__ b4d,
                            float* __restrict__ out) {
    __shared__ float h[128], t1[128], t2[64];
    const int t = threadIdx.x;
    h[t] = hsum[t] * (1.f / 32768.f);
    __syncthreads();
    float a = b2d[t];
    for (int j = 0; j < 128; j++) a += W2d[t * 128 + j] * h[j];
    t1[t] = lrelu(a);
    __syncthreads();
    if (t < 64) {
        float a2 = b3d[t];
        for (int j = 0; j < 128; j++) a2 += W3d[t * 128 + j] * t1[j];
        t2[t] = lrelu(a2);
    }
    __syncthreads();
    if (t < 11) {
        float a3 = b4d[t];
        for (int j = 0; j < 64; j++) a3 += W4d[t * 64 + j] * t2[j];
        out[t] = lrelu(a3);
    }
}

extern "C" void kernel_launch(void* const* d_in, const int* in_sizes, int n_in,
                              void* d_out, int out_size, void* d_ws, size_t ws_size,
                              hipStream_t stream) {
    const float* x   = (const float*)d_in[0];
    const float* w1  = (const float*)d_in[1];
    const float* g1  = (const float*)d_in[2];
    const float* b1  = (const float*)d_in[3];
    const float* w2  = (const float*)d_in[4];
    const float* g2  = (const float*)d_in[5];
    const float* b2  = (const float*)d_in[6];
    const float* wd1 = (const float*)d_in[7];
    const float* gd1 = (const float*)d_in[8];
    const float* bd1 = (const float*)d_in[9];
    const float* wd2 = (const float*)d_in[10];
    const float* gd2 = (const float*)d_in[11];
    const float* bd2 = (const float*)d_in[12];
    const float* W2d = (const float*)d_in[13];
    const float* b2d = (const float*)d_in[14];
    const float* W3d = (const float*)d_in[15];
    const float* b3d = (const float*)d_in[16];
    const float* W4d = (const float*)d_in[17];
    const float* b4d = (const float*)d_in[18];
    float* out = (float*)d_out;

    char* ws = (char*)d_ws;
    size_t off = 0;
    auto alloc = [&](size_t bytes) { char* p = ws + off; off += (bytes + 255) & ~size_t(255); return p; };
    int*   idx1  = (int*)  alloc(BB * NN * KK * 4);
    int*   idx2  = (int*)  alloc(BB * NN * KK * 4);
    int*   idx3  = (int*)  alloc(BB * NN * KK * 4);
    float* x1m   = (float*)alloc(BB * 32 * NN * 4);
    float* x2m   = (float*)alloc(BB * 64 * NN * 4);
    float* xd1   = (float*)alloc(BB * 64 * NN * 4);
    float* xd2   = (float*)alloc(BB * 64 * NN * 4);
    float* G1    = (float*)alloc((size_t)BB * NN * 64 * 4);   // 8.39MB, contiguous with G2
    float* G2    = (float*)alloc((size_t)BB * NN * 64 * 4);
    float* H     = (float*)alloc((size_t)BB * NN * 64 * 4);
    float* Vbuf  = (float*)alloc((size_t)BB * NN * 64 * 4);
    float* stats = (float*)alloc(4 * 256 * 4);    // 4 slabs: conv1/conv2/convd1/convd2
    float* hsum  = (float*)alloc(128 * 4);

    float* st0 = stats;
    float* st1 = stats + 256;
    float* st2 = stats + 512;
    float* st3 = stats + 768;

    // pk placements (all dead-buffer reuse, verified under stream order):
    //  pk3  (2.6MB) -> Vbuf       (Vbuf first written by conv1 stats, after knn3)
    //  pk32 (4.7MB) -> G2         (G2 next written by pre2, after knn32)
    //  pk64 (8.9MB) -> G1 + 0.5MB spill into G2 head (both dead after conv2
    //                  stats; knn64 runs before convd1's precompute rewrites G2)
    unsigned short* pk3  = (unsigned short*)Vbuf;
    unsigned short* pk32 = (unsigned short*)G2;
    unsigned short* pk64 = (unsigned short*)G1;

    const float invP = 1.f / (float)(BB * NN * KK);
    const dim3 knn_grid(NN / 64 * BB);     // 1D: b = id & 7 (XCD pinning)
    const dim3 pre_grid(NN / 64 * BB);

    // one upfront zero: 4 stats slabs (1024 floats) + hsum (128), contiguous.
    zero_kernel<<<5, 256, 0, stream>>>(stats, 1024 + 128);

    // --- kNN on x (C=3) ---
    pack3_kernel<<<NN / 256 * BB, 256, 0, stream>>>(x, pk3);
    knn_kernel<3><<<knn_grid, 256, 0, stream>>>(x, pk3, idx1);

    // --- conv1: Cout=32, group (x, idx1, C=3), w1 CIN=6 ---
    precompute_kernel<32><<<pre_grid, dim3(32, 8), 2 * 3 * 32 * 4, stream>>>(
        x, 3, w1, 6, 0, 3, G1, H);
    conv_stats_kernel<32, 1><<<NN / 8 * BB, dim3(32, 8), 0, stream>>>(
        G1, idx1, nullptr, nullptr, H, g1, st0, Vbuf);
    applypack_kernel<32><<<pre_grid, 256, 0, stream>>>(Vbuf, st0, g1, b1, x1m, pk32, invP);

    // --- kNN on x1_max (C=32) ---
    knn_kernel<32><<<knn_grid, 256, 0, stream>>>(x1m, pk32, idx2);

    // --- conv2: Cout=64, groups (x, idx1, 3) + (x1m, idx2, 32), w2 CIN=70 ---
    precompute2_kernel<<<pre_grid, dim3(64, 4), 0, stream>>>(x, x1m, w2, G1, G2, H);
    conv_stats_kernel<64, 2><<<NN / 4 * BB, dim3(64, 4), 0, stream>>>(
        G1, idx1, G2, idx2, H, g2, st1, Vbuf);
    applypack_kernel<64><<<pre_grid, 256, 0, stream>>>(Vbuf, st1, g2, b2, x2m, pk64, invP);

    // --- kNN on x2_max (C=64): moved before convd1 (convd1's precompute would
    //     clobber pk64's spill into G2) ---
    knn_kernel<64><<<knn_grid, 256, 0, stream>>>(x2m, pk64, idx3);

    // --- convd1: Cout=64, group (x1m, idx2, 32), wd1 CIN=64 ---
    precompute_kernel<64><<<pre_grid, dim3(64, 4), 2 * 32 * 64 * 4, stream>>>(
        x1m, 32, wd1, 64, 0, 32, G2, H);
    conv_stats_kernel<64, 1><<<NN / 4 * BB, dim3(64, 4), 0, stream>>>(
        G2, idx2, nullptr, nullptr, H, gd1, st2, Vbuf);
    apply_t_kernel<<<pre_grid, 256, 0, stream>>>(Vbuf, st2, gd1, bd1, xd1, invP);

    // --- convd2: Cout=64, group (x2m, idx3, 64), wd2 CIN=128 ---
    precompute_kernel<64><<<pre_grid, dim3(64, 4), 2 * 64 * 64 * 4, stream>>>(
        x2m, 64, wd2, 128, 0, 64, G1, H);
    conv_stats_kernel<64, 1><<<NN / 4 * BB, dim3(64, 4), 0, stream>>>(
        G1, idx3, nullptr, nullptr, H, gd2, st3, Vbuf);
    apply_t_kernel<<<pre_grid, 256, 0, stream>>>(Vbuf, st3, gd2, bd2, xd2, invP);

    // --- global mean + MLP head ---
    mean_kernel<<<1024, 256, 0, stream>>>(xd1, xd2, hsum);
    head_kernel<<<1, 128, 0, stream>>>(hsum, W2d, b2d, W3d, b3d, W4d, b4d, out);
}

// Round 18
// 1590.945 us; speedup vs baseline: 1.1455x; 1.0099x over previous
//
#include <hip/hip_runtime.h>

#define BB 8
#define NN 4096
#define KK 20
constexpr float EPSV = 1e-5f;
constexpr float SLOPE = 0.2f;

typedef __bf16 bfrag __attribute__((ext_vector_type(8)));
typedef float floatx4 __attribute__((ext_vector_type(4)));
typedef unsigned short us4 __attribute__((ext_vector_type(4)));
typedef unsigned short us8 __attribute__((ext_vector_type(8)));

__device__ __forceinline__ float lrelu(float v) { return v >= 0.f ? v : SLOPE * v; }

__device__ __forceinline__ unsigned short bf16rn(float f) {
    unsigned int u = __float_as_uint(f);
    return (unsigned short)((u + 0x7FFFu + ((u >> 16) & 1u)) >> 16);
}
__device__ __forceinline__ float bf16up(unsigned short h) {
    return __uint_as_float(((unsigned int)h) << 16);
}

// async global->LDS DMA, 16B per lane; lds dest must be wave-uniform base.
__device__ __forceinline__ void gl_lds16(const unsigned short* g, unsigned short* l) {
    __builtin_amdgcn_global_load_lds((const __attribute__((address_space(1))) void*)g,
                                     (__attribute__((address_space(3))) void*)l, 16, 0, 0);
}

__global__ void zero_kernel(float* p, int n) {
    int i = blockIdx.x * 256 + threadIdx.x;
    if (i < n) p[i] = 0.f;
}

// C=3 B-pack: [h3 l3 l3 h3 | 0 x20 | hn fp32 | 0 x6] per point (SK=40), hn inline.
__global__ void pack3_kernel(const float* __restrict__ src, unsigned short* __restrict__ pk) {
    const int id = blockIdx.x;
    const int b = id & 7;
    const int m = (id >> 3) * 256 + threadIdx.x;
    us8 w0, w1;
    #pragma unroll
    for (int j = 0; j < 8; j++) { w0[j] = 0; w1[j] = 0; }
    unsigned short row[12];
    float s = 0.f;
    #pragma unroll
    for (int c = 0; c < 3; c++) {
        float v = src[(b * 3 + c) * NN + m];
        s += v * v;
        unsigned short h = bf16rn(v);
        unsigned short l = bf16rn(v - bf16up(h));
        row[c] = h; row[3 + c] = l; row[6 + c] = l; row[9 + c] = h;
    }
    #pragma unroll
    for (int j = 0; j < 8; j++) w0[j] = row[j];
    #pragma unroll
    for (int j = 0; j < 4; j++) w1[j] = row[8 + j];
    unsigned short* dst = pk + (size_t)(b * NN + m) * 40;
    us8 z;
    #pragma unroll
    for (int j = 0; j < 8; j++) z[j] = 0;
    unsigned int ub = __float_as_uint(0.5f * s);
    us8 zh = z;
    zh[0] = (unsigned short)(ub & 0xFFFFu);
    zh[1] = (unsigned short)(ub >> 16);
    *(us8*)(dst) = w0;
    *(us8*)(dst + 8) = w1;
    *(us8*)(dst + 16) = z;
    *(us8*)(dst + 24) = z;
    *(us8*)(dst + 32) = zh;
}

// ---------------- kNN via MFMA (bf16 hi/lo split, 4-term exact) ----------------
// ROUND-7 VERBATIM (best measured: 254us C=64). 64 q/block, 2 blocks/CU,
// double-buffered global_load_lds staging, hn in row pad, exact running tau,
// pool + tid<64 drain, 2 __syncthreads per chunk, XCD pinning.
template<int C>
__global__ __launch_bounds__(256) void knn_kernel(const float* __restrict__ src,
                                                  const unsigned short* __restrict__ pk,
                                                  int* __restrict__ idx) {
    constexpr int SK = (C == 3) ? 40 : (2 * C + 8);   // padded k-stride (shorts)
    constexpr int HNOFF = (C == 3) ? 32 : 2 * C;      // hn fp32 offset in row
    constexpr int UNITS = 8 * SK;                     // 16B units per 64-row chunk
    constexpr int PF = (UNITS + 255) / 256;
    constexpr int KKN = (C == 3) ? 1 : (C / 32);
    __shared__ __attribute__((aligned(16))) unsigned short cpack[2 * 64 * SK];
    __shared__ float pv[64 * 65];
    __shared__ unsigned short pidx[64 * 66];
    __shared__ float tau[64];
    __shared__ int cnt[64];
    __shared__ unsigned short qls[(C == 3) ? 64 * 40 : 2];

    const int bid = blockIdx.x;
    const int b = bid & 7;               // batch -> XCD (wgid % 8 round-robin)
    const int q0 = (bid >> 3) * 64;
    const int tid = threadIdx.x;
    const int lane = tid & 63;
    const int wv = tid >> 6;
    const int wr = (wv >> 1) * 32;      // wave q-offset in [0,64)
    const int wc = (wv & 1) * 32;       // wave m-offset in [0,64)
    const int fl = lane & 15;
    const int fq = lane >> 4;

    float tv[20]; int ti[20];
    #pragma unroll
    for (int k = 0; k < 20; k++) { tv[k] = -3.4e38f; ti[k] = 0; }

    // ---- A fragments (registers, once) ----
    bfrag qah[KKN][2], qal[KKN][2];
    if (C == 3) {
        for (int i = tid; i < 64 * 20; i += 256) {
            int r = i / 20, k = 12 + i % 20;
            qls[r * 40 + k] = 0;
        }
        if (tid < 64) {
            #pragma unroll
            for (int c = 0; c < 3; c++) {
                float v = src[(b * 3 + c) * NN + q0 + tid];
                unsigned short h = bf16rn(v);
                unsigned short l = bf16rn(v - bf16up(h));
                // A-pack: [h3 l3 h3 l3 | 0...] pairs with B-pack [h3 l3 l3 h3]
                qls[tid * 40 + c] = h;  qls[tid * 40 + 3 + c] = l;
                qls[tid * 40 + 6 + c] = h;  qls[tid * 40 + 9 + c] = l;
            }
        }
    } else {
        #pragma unroll
        for (int r2 = 0; r2 < 2; r2++) {
            const unsigned short* qr = pk + (size_t)(b * NN + q0 + wr + r2 * 16 + fl) * SK + fq * 8;
            #pragma unroll
            for (int kk = 0; kk < KKN; kk++) {
                qah[kk][r2] = *(const bfrag*)(qr + kk * 32);
                qal[kk][r2] = *(const bfrag*)(qr + C + kk * 32);
            }
        }
    }

    // ---- prologue: async-stage chunk 0 into buffer 0 ----
    {
        const unsigned short* p0 = pk + (size_t)(b * NN) * SK;
        #pragma unroll
        for (int r = 0; r < PF; r++) {
            int u0 = r * 256 + wv * 64;          // wave-uniform base unit
            if (u0 < UNITS)
                gl_lds16(p0 + (size_t)(u0 + lane) * 8, cpack + (size_t)u0 * 8);
        }
    }
    if (tid < 64) { tau[tid] = -3.4e38f; cnt[tid] = 0; }
    __syncthreads();    // drains vmcnt: chunk 0 resident

    bfrag qa3[2];
    if (C == 3) {
        #pragma unroll
        for (int r2 = 0; r2 < 2; r2++)
            qa3[r2] = *(const bfrag*)(&qls[(wr + r2 * 16 + fl) * 40 + fq * 8]);
    }

    int buf = 0;
    for (int ch = 0; ch < 64; ch++) {
        unsigned short* cur = cpack + buf * (64 * SK);
        // ---- Phase A: issue async stage of ch+1; MFMA + filter on cur ----
        if (ch + 1 < 64) {
            unsigned short* nxt = cpack + (buf ^ 1) * (64 * SK);
            const unsigned short* pn = pk + (size_t)(b * NN + (ch + 1) * 64) * SK;
            #pragma unroll
            for (int r = 0; r < PF; r++) {
                int u0 = r * 256 + wv * 64;
                if (u0 < UNITS)
                    gl_lds16(pn + (size_t)(u0 + lane) * 8, nxt + (size_t)u0 * 8);
            }
        }

        floatx4 acc[2][2];
        #pragma unroll
        for (int r2 = 0; r2 < 2; r2++)
            #pragma unroll
            for (int c2 = 0; c2 < 2; c2++)
                acc[r2][c2] = (floatx4)(0.f);

        if (C == 3) {
            #pragma unroll
            for (int c2 = 0; c2 < 2; c2++) {
                bfrag bm = *(const bfrag*)(&cur[(wc + c2 * 16 + fl) * SK + fq * 8]);
                #pragma unroll
                for (int r2 = 0; r2 < 2; r2++)
                    acc[r2][c2] = __builtin_amdgcn_mfma_f32_16x16x32_bf16(qa3[r2], bm, acc[r2][c2], 0, 0, 0);
            }
        } else {
            #pragma unroll
            for (int kk = 0; kk < KKN; kk++) {
                const int kb = kk * 32 + fq * 8;
                bfrag bh[2], bl[2];
                #pragma unroll
                for (int c2 = 0; c2 < 2; c2++) {
                    bh[c2] = *(const bfrag*)(&cur[(wc + c2 * 16 + fl) * SK + kb]);
                    bl[c2] = *(const bfrag*)(&cur[(wc + c2 * 16 + fl) * SK + C + kb]);
                }
                #pragma unroll
                for (int r2 = 0; r2 < 2; r2++)
                    #pragma unroll
                    for (int c2 = 0; c2 < 2; c2++) {
                        acc[r2][c2] = __builtin_amdgcn_mfma_f32_16x16x32_bf16(qah[kk][r2], bh[c2], acc[r2][c2], 0, 0, 0);
                        acc[r2][c2] = __builtin_amdgcn_mfma_f32_16x16x32_bf16(qah[kk][r2], bl[c2], acc[r2][c2], 0, 0, 0);
                        acc[r2][c2] = __builtin_amdgcn_mfma_f32_16x16x32_bf16(qal[kk][r2], bh[c2], acc[r2][c2], 0, 0, 0);
                        acc[r2][c2] = __builtin_amdgcn_mfma_f32_16x16x32_bf16(qal[kk][r2], bl[c2], acc[r2][c2], 0, 0, 0);
                    }
            }
        }

        // ---- filter: C-layout col=lane&15 (m), row=fq*4+reg (q); exact tau;
        //      hn read from the staged row pad in LDS ----
        {
            const int m0 = ch * 64;
            float hvv[2];
            #pragma unroll
            for (int c2 = 0; c2 < 2; c2++)
                hvv[c2] = *(const float*)(&cur[(wc + c2 * 16 + fl) * SK + HNOFF]);
            #pragma unroll
            for (int r2 = 0; r2 < 2; r2++) {
                const int qb = wr + r2 * 16 + fq * 4;
                float4 t4 = *(const float4*)(&tau[qb]);
                float ta[4] = { t4.x, t4.y, t4.z, t4.w };
                #pragma unroll
                for (int c2 = 0; c2 < 2; c2++) {
                    const float hv = hvv[c2];
                    const int mm = m0 + wc + c2 * 16 + fl;
                    #pragma unroll
                    for (int reg = 0; reg < 4; reg++) {
                        float s = acc[r2][c2][reg] - hv;
                        if (s > ta[reg]) {
                            int q = qb + reg;
                            int p = atomicAdd(&cnt[q], 1);   // <= 64 per chunk: fits
                            pv[q * 65 + p] = s;
                            pidx[q * 66 + p] = (unsigned short)mm;
                        }
                    }
                }
            }
        }
        __syncthreads();   // B1: pool complete; vmcnt(0) -> next chunk resident

        // ---- Phase B: drain (tid<64, lane-parallel over q); exact top-20 + tau ----
        if (tid < 64) {
            int n = cnt[tid];
            for (int t = 0; t < n; t++) {
                float v = pv[tid * 65 + t];
                if (v > tv[0]) {
                    tv[0] = v; ti[0] = (int)pidx[tid * 66 + t];
                    #pragma unroll
                    for (int j = 0; j < 19; j++) {
                        if (tv[j] > tv[j + 1]) {
                            float a = tv[j]; tv[j] = tv[j + 1]; tv[j + 1] = a;
                            int bi = ti[j]; ti[j] = ti[j + 1]; ti[j + 1] = bi;
                        }
                    }
                }
            }
            cnt[tid] = 0;
            tau[tid] = tv[0];
        }
        __syncthreads();   // B2: tau/cnt ready
        buf ^= 1;
    }

    if (tid < 64) {
        #pragma unroll
        for (int k = 0; k < 20; k++)
            idx[(b * NN + q0 + tid) * KK + k] = ti[k];   // order irrelevant downstream
    }
}

// ---------------- conv precompute: G = Wd*src, H = (Wc-Wd)*src ----------------
// XCD-pinned: b = blockIdx.x & 7.
template<int COUT>
__global__ void precompute_kernel(const float* __restrict__ src, int C,
                                  const float* __restrict__ w, int CIN, int wd_off, int wc_off,
                                  float* __restrict__ G, float* __restrict__ H) {
    constexpr int MY = 256 / COUT;
    extern __shared__ float lds[];
    float* wd = lds;
    float* wc = lds + C * COUT;
    const int id = blockIdx.x;
    const int b = id & 7;
    const int m_base = (id >> 3) * 64;
    const int tid = threadIdx.y * COUT + threadIdx.x;
    for (int i = tid; i < C * COUT; i += 256) {
        int c = i / COUT, o = i % COUT;
        float a  = w[o * CIN + wd_off + c];
        float cc = w[o * CIN + wc_off + c];
        wd[i] = a;
        wc[i] = cc - a;
    }
    __syncthreads();
    const int o = threadIdx.x;
    for (int it = 0; it < COUT / 4; it++) {
        int m = m_base + it * MY + threadIdx.y;
        float g = 0.f, h = 0.f;
        for (int c = 0; c < C; c++) {
            float s = src[(b * C + c) * NN + m];
            g += wd[c * COUT + o] * s;
            h += wc[c * COUT + o] * s;
        }
        int gi = (b * NN + m) * COUT + o;
        G[gi] = g;
        H[gi] = h;
    }
}

// conv2 fused dual-source precompute: SEPARATE GA (x, offs 0/3) and GB (x1m,
// offs 6/38) + combined H. One pass, one dispatch, no H read-modify-write.
__global__ void precompute2_kernel(const float* __restrict__ srcA, const float* __restrict__ srcB,
                                   const float* __restrict__ w,
                                   float* __restrict__ GA, float* __restrict__ GB,
                                   float* __restrict__ H) {
    constexpr int COUT = 64, CA = 3, CB = 32, CIN = 70;
    __shared__ float wdA[CA * COUT], wcA[CA * COUT], wdB[CB * COUT], wcB[CB * COUT];
    const int id = blockIdx.x;
    const int b = id & 7;
    const int m_base = (id >> 3) * 64;
    const int tid = threadIdx.y * COUT + threadIdx.x;
    for (int i = tid; i < CA * COUT; i += 256) {
        int c = i / COUT, o = i % COUT;
        float a = w[o * CIN + 0 + c], cc = w[o * CIN + 3 + c];
        wdA[i] = a; wcA[i] = cc - a;
    }
    for (int i = tid; i < CB * COUT; i += 256) {
        int c = i / COUT, o = i % COUT;
        float a = w[o * CIN + 6 + c], cc = w[o * CIN + 38 + c];
        wdB[i] = a; wcB[i] = cc - a;
    }
    __syncthreads();
    const int o = threadIdx.x;
    for (int it = 0; it < 16; it++) {
        int m = m_base + it * 4 + threadIdx.y;
        float ga = 0.f, gb = 0.f, h = 0.f;
        for (int c = 0; c < CA; c++) {
            float s = srcA[(b * CA + c) * NN + m];
            ga += wdA[c * COUT + o] * s;
            h  += wcA[c * COUT + o] * s;
        }
        for (int c = 0; c < CB; c++) {
            float s = srcB[(b * CB + c) * NN + m];
            gb += wdB[c * COUT + o] * s;
            h  += wcB[c * COUT + o] * s;
        }
        int gi = (b * NN + m) * COUT + o;
        GA[gi] = ga;
        GB[gi] = gb;
        H[gi] = h;
    }
}

// ---------------- conv stats + per-(b,n,o) selected extreme over k -------------
// sign(sc) = sign(g[o]) (rsqrt > 0): write single V = chosen extreme + h.
// XCD-pinned: b = blockIdx.x & 7 -> batch-b G-rows L2-resident.
template<int COUT, int GROUPS>
__global__ void conv_stats_kernel(const float* __restrict__ G1, const int* __restrict__ idx1,
                                  const float* __restrict__ G2, const int* __restrict__ idx2,
                                  const float* __restrict__ H, const float* __restrict__ gw,
                                  float* __restrict__ stats, float* __restrict__ V) {
    constexpr int NY = 256 / COUT;
    const int id = blockIdx.x;
    const int b = id & 7;
    const int o = threadIdx.x;
    const int n = (id >> 3) * NY + threadIdx.y;
    const int base = b * NN + n;
    const float h = H[base * COUT + o];
    float s1 = 0.f, s2 = 0.f;
    float gx = -3.4e38f, gn = 3.4e38f;
    #pragma unroll
    for (int k = 0; k < KK; k++) {
        int i1 = idx1[base * KK + k];
        float g = G1[(b * NN + i1) * COUT + o];
        if (GROUPS == 2) {
            int i2 = idx2[base * KK + k];
            g += G2[(b * NN + i2) * COUT + o];
        }
        float y = g + h;
        s1 += y;
        s2 += y * y;
        gx = fmaxf(gx, g);
        gn = fminf(gn, g);
    }
    V[base * COUT + o] = ((gw[o] >= 0.f) ? gx : gn) + h;

    __shared__ float ls[2 * COUT];
    if (threadIdx.y == 0) { ls[o] = 0.f; ls[COUT + o] = 0.f; }
    __syncthreads();
    atomicAdd(&ls[o], s1);
    atomicAdd(&ls[COUT + o], s2);
    __syncthreads();
    if (threadIdx.y == 0) {
        atomicAdd(&stats[o], ls[o]);
        atomicAdd(&stats[64 + o], ls[COUT + o]);
    }
}

// ---------------- FUSED apply + channel-sum (xd1/xd2 never materialized) -------
// Reads V o-fast (wave = one n, lanes = 64 channels -> coalesced 256B), applies
// BN affine + lrelu, wave shuffle-reduces the channel sum, writes per-n LDS bin
// (no atomics: each (wave,iter) owns a unique n), then 64 XCD-LOCAL global
// atomics per block into hsum8[b*128 + ((m0+n)&127)] (b = bid&7 = XCD pin, so
// no cross-die contention; bin = n&127 identical to the reference reshape since
// the channel stride 4096 == 0 mod 128). head sums the 8 slabs.
__global__ void applysum_kernel(const float* __restrict__ V, const float* __restrict__ stats,
                                const float* __restrict__ g, const float* __restrict__ bb,
                                float* __restrict__ hsum8, float invP) {
    __shared__ float sc_s[64], sh_s[64];
    __shared__ float bins[64];
    const int id = blockIdx.x;
    const int b = id & 7;
    const int m0 = (id >> 3) * 64;
    const int tid = threadIdx.x;
    if (tid < 64) {
        float mu  = stats[tid] * invP;
        float var = stats[64 + tid] * invP - mu * mu;
        float sc  = g[tid] * rsqrtf(var + EPSV);
        sc_s[tid] = sc;
        sh_s[tid] = bb[tid] - mu * sc;
    }
    __syncthreads();
    const int o = tid & 63;
    const int grp = tid >> 6;
    #pragma unroll
    for (int it = 0; it < 16; it++) {
        int n = it * 4 + grp;
        float v = V[((size_t)(b * NN + m0 + n)) * 64 + o];
        float y = lrelu(sc_s[o] * v + sh_s[o]);
        #pragma unroll
        for (int s2 = 32; s2 > 0; s2 >>= 1) y += __shfl_down(y, s2, 64);
        if (o == 0) bins[n] = y;
    }
    __syncthreads();
    if (tid < 64)
        atomicAdd(&hsum8[b * 128 + ((m0 + tid) & 127)], bins[tid]);
}

// ---------------- FUSED apply + pack (for x1m, x2m) ----------------
// Reads V, applies BN affine + lrelu (finalize fused), writes BOTH the fp32
// tensor xm AND the bf16 hi/lo packed rows + hn pad for the next kNN.
// Pad region [2C+2,2C+8) of each pk row is never read -> left unwritten.
// XCD-pinned: b = blockIdx.x & 7; block covers 64 points x COUT channels.
template<int COUT>
__global__ void applypack_kernel(const float* __restrict__ V, const float* __restrict__ stats,
                                 const float* __restrict__ g, const float* __restrict__ bb,
                                 float* __restrict__ xm, unsigned short* __restrict__ pk,
                                 float invP) {
    constexpr int SK = 2 * COUT + 8;
    constexpr int Q = COUT / 4;          // channels per thread (4 threads/point)
    __shared__ float sc_s[COUT], sh_s[COUT], hnacc[64];
    const int id = blockIdx.x;
    const int b = id & 7;
    const int m0 = (id >> 3) * 64;
    const int tid = threadIdx.x;
    if (tid < COUT) {
        float mu  = stats[tid] * invP;
        float var = stats[64 + tid] * invP - mu * mu;
        float sc  = g[tid] * rsqrtf(var + EPSV);
        sc_s[tid] = sc;
        sh_s[tid] = bb[tid] - mu * sc;
    }
    if (tid < 64) hnacc[tid] = 0.f;
    __syncthreads();
    const int n = tid & 63;
    const int oc = (tid >> 6) * Q;
    const float* vp = V + ((size_t)(b * NN + m0 + n) * COUT + oc);
    float y[Q];
    float s = 0.f;
    #pragma unroll
    for (int j = 0; j < Q; j++) {
        float yy = lrelu(sc_s[oc + j] * vp[j] + sh_s[oc + j]);
        y[j] = yy;
        s += yy * yy;
        xm[(b * COUT + oc + j) * NN + m0 + n] = yy;
    }
    atomicAdd(&hnacc[n], s);
    unsigned short* pr = pk + (size_t)(b * NN + m0 + n) * SK;
    #pragma unroll
    for (int j4 = 0; j4 < Q / 4; j4++) {
        us4 hv, lv;
        #pragma unroll
        for (int j = 0; j < 4; j++) {
            float yy = y[j4 * 4 + j];
            unsigned short h = bf16rn(yy);
            hv[j] = h;
            lv[j] = bf16rn(yy - bf16up(h));
        }
        *(us4*)(pr + oc + j4 * 4) = hv;
        *(us4*)(pr + COUT + oc + j4 * 4) = lv;
    }
    __syncthreads();
    if (tid < 64)
        *(unsigned int*)(pk + (size_t)(b * NN + m0 + tid) * SK + 2 * COUT) =
            __float_as_uint(0.5f * hnacc[tid]);
}

__global__ void head_kernel(const float* __restrict__ hsum8,
                            const float* __restrict__ W2d, const float* __restrict__ b2d,
                            const float* __restrict__ W3d, const float* __restrict__ b3d,
                            const float* __restrict__ W4d, const float* __restrict__ b4d,
                            float* __restrict__ out) {
    __shared__ float h[128], t1[128], t2[64];
    const int t = threadIdx.x;
    float acc = 0.f;
    #pragma unroll
    for (int sl = 0; sl < 8; sl++) acc += hsum8[sl * 128 + t];
    h[t] = acc * (1.f / 32768.f);
    __syncthreads();
    float a = b2d[t];
    for (int j = 0; j < 128; j++) a += W2d[t * 128 + j] * h[j];
    t1[t] = lrelu(a);
    __syncthreads();
    if (t < 64) {
        float a2 = b3d[t];
        for (int j = 0; j < 128; j++) a2 += W3d[t * 128 + j] * t1[j];
        t2[t] = lrelu(a2);
    }
    __syncthreads();
    if (t < 11) {
        float a3 = b4d[t];
        for (int j = 0; j < 64; j++) a3 += W4d[t * 64 + j] * t2[j];
        out[t] = lrelu(a3);
    }
}

extern "C" void kernel_launch(void* const* d_in, const int* in_sizes, int n_in,
                              void* d_out, int out_size, void* d_ws, size_t ws_size,
                              hipStream_t stream) {
    const float* x   = (const float*)d_in[0];
    const float* w1  = (const float*)d_in[1];
    const float* g1  = (const float*)d_in[2];
    const float* b1  = (const float*)d_in[3];
    const float* w2  = (const float*)d_in[4];
    const float* g2  = (const float*)d_in[5];
    const float* b2  = (const float*)d_in[6];
    const float* wd1 = (const float*)d_in[7];
    const float* gd1 = (const float*)d_in[8];
    const float* bd1 = (const float*)d_in[9];
    const float* wd2 = (const float*)d_in[10];
    const float* gd2 = (const float*)d_in[11];
    const float* bd2 = (const float*)d_in[12];
    const float* W2d = (const float*)d_in[13];
    const float* b2d = (const float*)d_in[14];
    const float* W3d = (const float*)d_in[15];
    const float* b3d = (const float*)d_in[16];
    const float* W4d = (const float*)d_in[17];
    const float* b4d = (const float*)d_in[18];
    float* out = (float*)d_out;

    char* ws = (char*)d_ws;
    size_t off = 0;
    auto alloc = [&](size_t bytes) { char* p = ws + off; off += (bytes + 255) & ~size_t(255); return p; };
    int*   idx1  = (int*)  alloc(BB * NN * KK * 4);
    int*   idx2  = (int*)  alloc(BB * NN * KK * 4);
    int*   idx3  = (int*)  alloc(BB * NN * KK * 4);
    float* x1m   = (float*)alloc(BB * 32 * NN * 4);
    float* x2m   = (float*)alloc(BB * 64 * NN * 4);
    float* G1    = (float*)alloc((size_t)BB * NN * 64 * 4);   // contiguous with G2 (pk64 spill)
    float* G2    = (float*)alloc((size_t)BB * NN * 64 * 4);
    float* H     = (float*)alloc((size_t)BB * NN * 64 * 4);
    float* Vbuf  = (float*)alloc((size_t)BB * NN * 64 * 4);
    float* stats = (float*)alloc(4 * 256 * 4);    // 4 slabs: conv1/conv2/convd1/convd2
    float* hsum8 = (float*)alloc(8 * 128 * 4);    // per-XCD mean slabs (contig w/ stats)

    float* st0 = stats;
    float* st1 = stats + 256;
    float* st2 = stats + 512;
    float* st3 = stats + 768;

    // pk placements (all dead-buffer reuse, verified under stream order):
    //  pk3  (2.6MB) -> Vbuf       (Vbuf first written by conv1 stats, after knn3)
    //  pk32 (4.7MB) -> G2         (G2 next written by pre2, after knn32)
    //  pk64 (8.9MB) -> G1 + 0.5MB spill into G2 head (both dead after conv2
    //                  stats; knn64 runs before convd1's precompute rewrites G2)
    unsigned short* pk3  = (unsigned short*)Vbuf;
    unsigned short* pk32 = (unsigned short*)G2;
    unsigned short* pk64 = (unsigned short*)G1;

    const float invP = 1.f / (float)(BB * NN * KK);
    const dim3 knn_grid(NN / 64 * BB);     // 1D: b = id & 7 (XCD pinning)
    const dim3 pre_grid(NN / 64 * BB);

    // one upfront zero: 4 stats slabs (1024) + hsum8 (1024), contiguous.
    zero_kernel<<<8, 256, 0, stream>>>(stats, 1024 + 1024);

    // --- kNN on x (C=3) ---
    pack3_kernel<<<NN / 256 * BB, 256, 0, stream>>>(x, pk3);
    knn_kernel<3><<<knn_grid, 256, 0, stream>>>(x, pk3, idx1);

    // --- conv1: Cout=32, group (x, idx1, C=3), w1 CIN=6 ---
    precompute_kernel<32><<<pre_grid, dim3(32, 8), 2 * 3 * 32 * 4, stream>>>(
        x, 3, w1, 6, 0, 3, G1, H);
    conv_stats_kernel<32, 1><<<NN / 8 * BB, dim3(32, 8), 0, stream>>>(
        G1, idx1, nullptr, nullptr, H, g1, st0, Vbuf);
    applypack_kernel<32><<<pre_grid, 256, 0, stream>>>(Vbuf, st0, g1, b1, x1m, pk32, invP);

    // --- kNN on x1_max (C=32) ---
    knn_kernel<32><<<knn_grid, 256, 0, stream>>>(x1m, pk32, idx2);

    // --- conv2: Cout=64, groups (x, idx1, 3) + (x1m, idx2, 32), w2 CIN=70 ---
    precompute2_kernel<<<pre_grid, dim3(64, 4), 0, stream>>>(x, x1m, w2, G1, G2, H);
    conv_stats_kernel<64, 2><<<NN / 4 * BB, dim3(64, 4), 0, stream>>>(
        G1, idx1, G2, idx2, H, g2, st1, Vbuf);
    applypack_kernel<64><<<pre_grid, 256, 0, stream>>>(Vbuf, st1, g2, b2, x2m, pk64, invP);

    // --- kNN on x2_max (C=64): before convd1 (its precompute clobbers pk64 spill) ---
    knn_kernel<64><<<knn_grid, 256, 0, stream>>>(x2m, pk64, idx3);

    // --- convd1: Cout=64, group (x1m, idx2, 32), wd1 CIN=64 ---
    precompute_kernel<64><<<pre_grid, dim3(64, 4), 2 * 32 * 64 * 4, stream>>>(
        x1m, 32, wd1, 64, 0, 32, G2, H);
    conv_stats_kernel<64, 1><<<NN / 4 * BB, dim3(64, 4), 0, stream>>>(
        G2, idx2, nullptr, nullptr, H, gd1, st2, Vbuf);
    applysum_kernel<<<pre_grid, 256, 0, stream>>>(Vbuf, st2, gd1, bd1, hsum8, invP);

    // --- convd2: Cout=64, group (x2m, idx3, 64), wd2 CIN=128 ---
    precompute_kernel<64><<<pre_grid, dim3(64, 4), 2 * 64 * 64 * 4, stream>>>(
        x2m, 64, wd2, 128, 0, 64, G1, H);
    conv_stats_kernel<64, 1><<<NN / 4 * BB, dim3(64, 4), 0, stream>>>(
        G1, idx3, nullptr, nullptr, H, gd2, st3, Vbuf);
    applysum_kernel<<<pre_grid, 256, 0, stream>>>(Vbuf, st3, gd2, bd2, hsum8, invP);

    // --- MLP head (sums the 8 per-XCD slabs) ---
    head_kernel<<<1, 128, 0, stream>>>(hsum8, W2d, b2d, W3d, b3d, W4d, b4d, out);
}

// Round 19
// 1588.444 us; speedup vs baseline: 1.1473x; 1.0016x over previous
//
#include <hip/hip_runtime.h>

#define BB 8
#define NN 4096
#define KK 20
constexpr float EPSV = 1e-5f;
constexpr float SLOPE = 0.2f;

typedef __bf16 bfrag __attribute__((ext_vector_type(8)));
typedef float floatx4 __attribute__((ext_vector_type(4)));
typedef unsigned short us4 __attribute__((ext_vector_type(4)));
typedef unsigned short us8 __attribute__((ext_vector_type(8)));

__device__ __forceinline__ float lrelu(float v) { return v >= 0.f ? v : SLOPE * v; }

__device__ __forceinline__ unsigned short bf16rn(float f) {
    unsigned int u = __float_as_uint(f);
    return (unsigned short)((u + 0x7FFFu + ((u >> 16) & 1u)) >> 16);
}
__device__ __forceinline__ float bf16up(unsigned short h) {
    return __uint_as_float(((unsigned int)h) << 16);
}

// async global->LDS DMA, 16B per lane; lds dest must be wave-uniform base.
__device__ __forceinline__ void gl_lds16(const unsigned short* g, unsigned short* l) {
    __builtin_amdgcn_global_load_lds((const __attribute__((address_space(1))) void*)g,
                                     (__attribute__((address_space(3))) void*)l, 16, 0, 0);
}

__global__ void zero_kernel(float* p, int n) {
    int i = blockIdx.x * 256 + threadIdx.x;
    if (i < n) p[i] = 0.f;
}

// C=3 B-pack: [h3 l3 l3 h3 | 0 x20 | hn fp32 | 0 x6] per point (SK=40), hn inline.
__global__ void pack3_kernel(const float* __restrict__ src, unsigned short* __restrict__ pk) {
    const int id = blockIdx.x;
    const int b = id & 7;
    const int m = (id >> 3) * 256 + threadIdx.x;
    us8 w0, w1;
    #pragma unroll
    for (int j = 0; j < 8; j++) { w0[j] = 0; w1[j] = 0; }
    unsigned short row[12];
    float s = 0.f;
    #pragma unroll
    for (int c = 0; c < 3; c++) {
        float v = src[(b * 3 + c) * NN + m];
        s += v * v;
        unsigned short h = bf16rn(v);
        unsigned short l = bf16rn(v - bf16up(h));
        row[c] = h; row[3 + c] = l; row[6 + c] = l; row[9 + c] = h;
    }
    #pragma unroll
    for (int j = 0; j < 8; j++) w0[j] = row[j];
    #pragma unroll
    for (int j = 0; j < 4; j++) w1[j] = row[8 + j];
    unsigned short* dst = pk + (size_t)(b * NN + m) * 40;
    us8 z;
    #pragma unroll
    for (int j = 0; j < 8; j++) z[j] = 0;
    unsigned int ub = __float_as_uint(0.5f * s);
    us8 zh = z;
    zh[0] = (unsigned short)(ub & 0xFFFFu);
    zh[1] = (unsigned short)(ub >> 16);
    *(us8*)(dst) = w0;
    *(us8*)(dst + 8) = w1;
    *(us8*)(dst + 16) = z;
    *(us8*)(dst + 24) = z;
    *(us8*)(dst + 32) = zh;
}

// ---------------- kNN via MFMA (bf16 hi/lo split, 4-term exact) ----------------
// Round-7 skeleton (best measured 254-258us C=64): 64 q/block, 2 blocks/CU,
// double-buffered global_load_lds staging, hn in row pad, exact running tau,
// pool + tid<64 drain, 2 __syncthreads per PHASE, XCD pinning.
// NEW: phase width MW = 128 for C=3 (skeleton cost is C-independent; knn3 is
// ~pure skeleton, so halving phase count halves barrier/drain events). Pool
// capacity 130 >= worst case 128 survivors/phase (phase 0, tau=-inf). C=32/64
// keep MW=64 (byte-identical to round 18).
template<int C>
__global__ __launch_bounds__(256) void knn_kernel(const float* __restrict__ src,
                                                  const unsigned short* __restrict__ pk,
                                                  int* __restrict__ idx) {
    constexpr int SK = (C == 3) ? 40 : (2 * C + 8);   // padded k-stride (shorts)
    constexpr int HNOFF = (C == 3) ? 32 : 2 * C;      // hn fp32 offset in row
    constexpr int MW = (C == 3) ? 128 : 64;           // m's per phase
    constexpr int NCH = NN / MW;                      // phases
    constexpr int UNITS = MW * SK / 8;                // 16B units per phase
    constexpr int PF = (UNITS + 255) / 256;
    constexpr int KKN = (C == 3) ? 1 : (C / 32);
    constexpr int PVS = (C == 3) ? 130 : 65;          // pool strides
    constexpr int PIS = (C == 3) ? 132 : 66;
    __shared__ __attribute__((aligned(16))) unsigned short cpack[2 * MW * SK];
    __shared__ float pv[64 * PVS];
    __shared__ unsigned short pidx[64 * PIS];
    __shared__ float tau[64];
    __shared__ int cnt[64];
    __shared__ unsigned short qls[(C == 3) ? 64 * 40 : 2];

    const int bid = blockIdx.x;
    const int b = bid & 7;               // batch -> XCD (wgid % 8 round-robin)
    const int q0 = (bid >> 3) * 64;
    const int tid = threadIdx.x;
    const int lane = tid & 63;
    const int wv = tid >> 6;
    const int wr = (wv >> 1) * 32;      // wave q-offset in [0,64)
    const int wc = (wv & 1) * 32;       // wave m-offset in [0,64)
    const int fl = lane & 15;
    const int fq = lane >> 4;

    float tv[20]; int ti[20];
    #pragma unroll
    for (int k = 0; k < 20; k++) { tv[k] = -3.4e38f; ti[k] = 0; }

    // ---- A fragments (registers, once) ----
    bfrag qah[KKN][2], qal[KKN][2];
    if (C == 3) {
        for (int i = tid; i < 64 * 20; i += 256) {
            int r = i / 20, k = 12 + i % 20;
            qls[r * 40 + k] = 0;
        }
        if (tid < 64) {
            #pragma unroll
            for (int c = 0; c < 3; c++) {
                float v = src[(b * 3 + c) * NN + q0 + tid];
                unsigned short h = bf16rn(v);
                unsigned short l = bf16rn(v - bf16up(h));
                // A-pack: [h3 l3 h3 l3 | 0...] pairs with B-pack [h3 l3 l3 h3]
                qls[tid * 40 + c] = h;  qls[tid * 40 + 3 + c] = l;
                qls[tid * 40 + 6 + c] = h;  qls[tid * 40 + 9 + c] = l;
            }
        }
    } else {
        #pragma unroll
        for (int r2 = 0; r2 < 2; r2++) {
            const unsigned short* qr = pk + (size_t)(b * NN + q0 + wr + r2 * 16 + fl) * SK + fq * 8;
            #pragma unroll
            for (int kk = 0; kk < KKN; kk++) {
                qah[kk][r2] = *(const bfrag*)(qr + kk * 32);
                qal[kk][r2] = *(const bfrag*)(qr + C + kk * 32);
            }
        }
    }

    // ---- prologue: async-stage phase 0 into buffer 0 ----
    {
        const unsigned short* p0 = pk + (size_t)(b * NN) * SK;
        #pragma unroll
        for (int r = 0; r < PF; r++) {
            int u0 = r * 256 + wv * 64;          // wave-uniform base unit
            if (u0 < UNITS)
                gl_lds16(p0 + (size_t)(u0 + lane) * 8, cpack + (size_t)u0 * 8);
        }
    }
    if (tid < 64) { tau[tid] = -3.4e38f; cnt[tid] = 0; }
    __syncthreads();    // drains vmcnt: phase 0 resident

    bfrag qa3[2];
    if (C == 3) {
        #pragma unroll
        for (int r2 = 0; r2 < 2; r2++)
            qa3[r2] = *(const bfrag*)(&qls[(wr + r2 * 16 + fl) * 40 + fq * 8]);
    }

    for (int ch = 0; ch < NCH; ch++) {
        unsigned short* cur = cpack + (ch & 1) * (MW * SK);
        // ---- Phase A: issue async stage of ch+1; MFMA + filter over MW m's ----
        if (ch + 1 < NCH) {
            unsigned short* nxt = cpack + ((ch + 1) & 1) * (MW * SK);
            const unsigned short* pn = pk + (size_t)(b * NN + (ch + 1) * MW) * SK;
            #pragma unroll
            for (int r = 0; r < PF; r++) {
                int u0 = r * 256 + wv * 64;
                if (u0 < UNITS)
                    gl_lds16(pn + (size_t)(u0 + lane) * 8, nxt + (size_t)u0 * 8);
            }
        }

        #pragma unroll
        for (int mh = 0; mh < MW / 64; mh++) {
            const unsigned short* sub = cur + mh * 64 * SK;
            floatx4 acc[2][2];
            #pragma unroll
            for (int r2 = 0; r2 < 2; r2++)
                #pragma unroll
                for (int c2 = 0; c2 < 2; c2++)
                    acc[r2][c2] = (floatx4)(0.f);

            if (C == 3) {
                #pragma unroll
                for (int c2 = 0; c2 < 2; c2++) {
                    bfrag bm = *(const bfrag*)(&sub[(wc + c2 * 16 + fl) * SK + fq * 8]);
                    #pragma unroll
                    for (int r2 = 0; r2 < 2; r2++)
                        acc[r2][c2] = __builtin_amdgcn_mfma_f32_16x16x32_bf16(qa3[r2], bm, acc[r2][c2], 0, 0, 0);
                }
            } else {
                #pragma unroll
                for (int kk = 0; kk < KKN; kk++) {
                    const int kb = kk * 32 + fq * 8;
                    bfrag bh[2], bl[2];
                    #pragma unroll
                    for (int c2 = 0; c2 < 2; c2++) {
                        bh[c2] = *(const bfrag*)(&sub[(wc + c2 * 16 + fl) * SK + kb]);
                        bl[c2] = *(const bfrag*)(&sub[(wc + c2 * 16 + fl) * SK + C + kb]);
                    }
                    #pragma unroll
                    for (int r2 = 0; r2 < 2; r2++)
                        #pragma unroll
                        for (int c2 = 0; c2 < 2; c2++) {
                            acc[r2][c2] = __builtin_amdgcn_mfma_f32_16x16x32_bf16(qah[kk][r2], bh[c2], acc[r2][c2], 0, 0, 0);
                            acc[r2][c2] = __builtin_amdgcn_mfma_f32_16x16x32_bf16(qah[kk][r2], bl[c2], acc[r2][c2], 0, 0, 0);
                            acc[r2][c2] = __builtin_amdgcn_mfma_f32_16x16x32_bf16(qal[kk][r2], bh[c2], acc[r2][c2], 0, 0, 0);
                            acc[r2][c2] = __builtin_amdgcn_mfma_f32_16x16x32_bf16(qal[kk][r2], bl[c2], acc[r2][c2], 0, 0, 0);
                        }
                }
            }

            // ---- filter: C-layout col=lane&15 (m), row=fq*4+reg (q); exact tau;
            //      hn read from the staged row pad in LDS ----
            {
                const int m0 = ch * MW + mh * 64;
                float hvv[2];
                #pragma unroll
                for (int c2 = 0; c2 < 2; c2++)
                    hvv[c2] = *(const float*)(&sub[(wc + c2 * 16 + fl) * SK + HNOFF]);
                #pragma unroll
                for (int r2 = 0; r2 < 2; r2++) {
                    const int qb = wr + r2 * 16 + fq * 4;
                    float4 t4 = *(const float4*)(&tau[qb]);
                    float ta[4] = { t4.x, t4.y, t4.z, t4.w };
                    #pragma unroll
                    for (int c2 = 0; c2 < 2; c2++) {
                        const float hv = hvv[c2];
                        const int mm = m0 + wc + c2 * 16 + fl;
                        #pragma unroll
                        for (int reg = 0; reg < 4; reg++) {
                            float s = acc[r2][c2][reg] - hv;
                            if (s > ta[reg]) {
                                int q = qb + reg;
                                int p = atomicAdd(&cnt[q], 1);   // <= MW per phase: fits PVS
                                pv[q * PVS + p] = s;
                                pidx[q * PIS + p] = (unsigned short)mm;
                            }
                        }
                    }
                }
            }
        }
        __syncthreads();   // B1: pool complete; vmcnt(0) -> next phase resident

        // ---- Phase B: drain (tid<64, lane-parallel over q); exact top-20 + tau ----
        if (tid < 64) {
            int n = cnt[tid];
            for (int t = 0; t < n; t++) {
                float v = pv[tid * PVS + t];
                if (v > tv[0]) {
                    tv[0] = v; ti[0] = (int)pidx[tid * PIS + t];
                    #pragma unroll
                    for (int j = 0; j < 19; j++) {
                        if (tv[j] > tv[j + 1]) {
                            float a = tv[j]; tv[j] = tv[j + 1]; tv[j + 1] = a;
                            int bi = ti[j]; ti[j] = ti[j + 1]; ti[j + 1] = bi;
                        }
                    }
                }
            }
            cnt[tid] = 0;
            tau[tid] = tv[0];
        }
        __syncthreads();   // B2: tau/cnt ready
    }

    if (tid < 64) {
        #pragma unroll
        for (int k = 0; k < 20; k++)
            idx[(b * NN + q0 + tid) * KK + k] = ti[k];   // order irrelevant downstream
    }
}

// ---------------- conv precompute: G = Wd*src, H = (Wc-Wd)*src ----------------
// XCD-pinned: b = blockIdx.x & 7.
template<int COUT>
__global__ void precompute_kernel(const float* __restrict__ src, int C,
                                  const float* __restrict__ w, int CIN, int wd_off, int wc_off,
                                  float* __restrict__ G, float* __restrict__ H) {
    constexpr int MY = 256 / COUT;
    extern __shared__ float lds[];
    float* wd = lds;
    float* wc = lds + C * COUT;
    const int id = blockIdx.x;
    const int b = id & 7;
    const int m_base = (id >> 3) * 64;
    const int tid = threadIdx.y * COUT + threadIdx.x;
    for (int i = tid; i < C * COUT; i += 256) {
        int c = i / COUT, o = i % COUT;
        float a  = w[o * CIN + wd_off + c];
        float cc = w[o * CIN + wc_off + c];
        wd[i] = a;
        wc[i] = cc - a;
    }
    __syncthreads();
    const int o = threadIdx.x;
    for (int it = 0; it < COUT / 4; it++) {
        int m = m_base + it * MY + threadIdx.y;
        float g = 0.f, h = 0.f;
        for (int c = 0; c < C; c++) {
            float s = src[(b * C + c) * NN + m];
            g += wd[c * COUT + o] * s;
            h += wc[c * COUT + o] * s;
        }
        int gi = (b * NN + m) * COUT + o;
        G[gi] = g;
        H[gi] = h;
    }
}

// conv2 fused dual-source precompute: SEPARATE GA (x, offs 0/3) and GB (x1m,
// offs 6/38) + combined H. One pass, one dispatch, no H read-modify-write.
__global__ void precompute2_kernel(const float* __restrict__ srcA, const float* __restrict__ srcB,
                                   const float* __restrict__ w,
                                   float* __restrict__ GA, float* __restrict__ GB,
                                   float* __restrict__ H) {
    constexpr int COUT = 64, CA = 3, CB = 32, CIN = 70;
    __shared__ float wdA[CA * COUT], wcA[CA * COUT], wdB[CB * COUT], wcB[CB * COUT];
    const int id = blockIdx.x;
    const int b = id & 7;
    const int m_base = (id >> 3) * 64;
    const int tid = threadIdx.y * COUT + threadIdx.x;
    for (int i = tid; i < CA * COUT; i += 256) {
        int c = i / COUT, o = i % COUT;
        float a = w[o * CIN + 0 + c], cc = w[o * CIN + 3 + c];
        wdA[i] = a; wcA[i] = cc - a;
    }
    for (int i = tid; i < CB * COUT; i += 256) {
        int c = i / COUT, o = i % COUT;
        float a = w[o * CIN + 6 + c], cc = w[o * CIN + 38 + c];
        wdB[i] = a; wcB[i] = cc - a;
    }
    __syncthreads();
    const int o = threadIdx.x;
    for (int it = 0; it < 16; it++) {
        int m = m_base + it * 4 + threadIdx.y;
        float ga = 0.f, gb = 0.f, h = 0.f;
        for (int c = 0; c < CA; c++) {
            float s = srcA[(b * CA + c) * NN + m];
            ga += wdA[c * COUT + o] * s;
            h  += wcA[c * COUT + o] * s;
        }
        for (int c = 0; c < CB; c++) {
            float s = srcB[(b * CB + c) * NN + m];
            gb += wdB[c * COUT + o] * s;
            h  += wcB[c * COUT + o] * s;
        }
        int gi = (b * NN + m) * COUT + o;
        GA[gi] = ga;
        GB[gi] = gb;
        H[gi] = h;
    }
}

// ---------------- conv stats + per-(b,n,o) selected extreme over k -------------
// sign(sc) = sign(g[o]) (rsqrt > 0): write single V = chosen extreme + h.
// XCD-pinned: b = blockIdx.x & 7 -> batch-b G-rows L2-resident.
template<int COUT, int GROUPS>
__global__ void conv_stats_kernel(const float* __restrict__ G1, const int* __restrict__ idx1,
                                  const float* __restrict__ G2, const int* __restrict__ idx2,
                                  const float* __restrict__ H, const float* __restrict__ gw,
                                  float* __restrict__ stats, float* __restrict__ V) {
    constexpr int NY = 256 / COUT;
    const int id = blockIdx.x;
    const int b = id & 7;
    const int o = threadIdx.x;
    const int n = (id >> 3) * NY + threadIdx.y;
    const int base = b * NN + n;
    const float h = H[base * COUT + o];
    float s1 = 0.f, s2 = 0.f;
    float gx = -3.4e38f, gn = 3.4e38f;
    #pragma unroll
    for (int k = 0; k < KK; k++) {
        int i1 = idx1[base * KK + k];
        float g = G1[(b * NN + i1) * COUT + o];
        if (GROUPS == 2) {
            int i2 = idx2[base * KK + k];
            g += G2[(b * NN + i2) * COUT + o];
        }
        float y = g + h;
        s1 += y;
        s2 += y * y;
        gx = fmaxf(gx, g);
        gn = fminf(gn, g);
    }
    V[base * COUT + o] = ((gw[o] >= 0.f) ? gx : gn) + h;

    __shared__ float ls[2 * COUT];
    if (threadIdx.y == 0) { ls[o] = 0.f; ls[COUT + o] = 0.f; }
    __syncthreads();
    atomicAdd(&ls[o], s1);
    atomicAdd(&ls[COUT + o], s2);
    __syncthreads();
    if (threadIdx.y == 0) {
        atomicAdd(&stats[o], ls[o]);
        atomicAdd(&stats[64 + o], ls[COUT + o]);
    }
}

// ---------------- FUSED apply + channel-sum (xd1/xd2 never materialized) -------
// Reads V o-fast (wave = one n, lanes = 64 channels -> coalesced 256B), applies
// BN affine + lrelu, wave shuffle-reduces the channel sum, writes per-n LDS bin
// (no atomics), then 64 XCD-LOCAL global atomics per block into
// hsum8[b*128 + ((m0+n)&127)] (b = bid&7 = XCD pin; bin = n&127 identical to
// the reference reshape since the channel stride 4096 == 0 mod 128).
__global__ void applysum_kernel(const float* __restrict__ V, const float* __restrict__ stats,
                                const float* __restrict__ g, const float* __restrict__ bb,
                                float* __restrict__ hsum8, float invP) {
    __shared__ float sc_s[64], sh_s[64];
    __shared__ float bins[64];
    const int id = blockIdx.x;
    const int b = id & 7;
    const int m0 = (id >> 3) * 64;
    const int tid = threadIdx.x;
    if (tid < 64) {
        float mu  = stats[tid] * invP;
        float var = stats[64 + tid] * invP - mu * mu;
        float sc  = g[tid] * rsqrtf(var + EPSV);
        sc_s[tid] = sc;
        sh_s[tid] = bb[tid] - mu * sc;
    }
    __syncthreads();
    const int o = tid & 63;
    const int grp = tid >> 6;
    #pragma unroll
    for (int it = 0; it < 16; it++) {
        int n = it * 4 + grp;
        float v = V[((size_t)(b * NN + m0 + n)) * 64 + o];
        float y = lrelu(sc_s[o] * v + sh_s[o]);
        #pragma unroll
        for (int s2 = 32; s2 > 0; s2 >>= 1) y += __shfl_down(y, s2, 64);
        if (o == 0) bins[n] = y;
    }
    __syncthreads();
    if (tid < 64)
        atomicAdd(&hsum8[b * 128 + ((m0 + tid) & 127)], bins[tid]);
}

// ---------------- FUSED apply + pack (for x1m, x2m) ----------------
// Reads V, applies BN affine + lrelu (finalize fused), writes BOTH the fp32
// tensor xm AND the bf16 hi/lo packed rows + hn pad for the next kNN.
// Pad region [2C+2,2C+8) of each pk row is never read -> left unwritten.
// XCD-pinned: b = blockIdx.x & 7; block covers 64 points x COUT channels.
template<int COUT>
__global__ void applypack_kernel(const float* __restrict__ V, const float* __restrict__ stats,
                                 const float* __restrict__ g, const float* __restrict__ bb,
                                 float* __restrict__ xm, unsigned short* __restrict__ pk,
                                 float invP) {
    constexpr int SK = 2 * COUT + 8;
    constexpr int Q = COUT / 4;          // channels per thread (4 threads/point)
    __shared__ float sc_s[COUT], sh_s[COUT], hnacc[64];
    const int id = blockIdx.x;
    const int b = id & 7;
    const int m0 = (id >> 3) * 64;
    const int tid = threadIdx.x;
    if (tid < COUT) {
        float mu  = stats[tid] * invP;
        float var = stats[64 + tid] * invP - mu * mu;
        float sc  = g[tid] * rsqrtf(var + EPSV);
        sc_s[tid] = sc;
        sh_s[tid] = bb[tid] - mu * sc;
    }
    if (tid < 64) hnacc[tid] = 0.f;
    __syncthreads();
    const int n = tid & 63;
    const int oc = (tid >> 6) * Q;
    const float* vp = V + ((size_t)(b * NN + m0 + n) * COUT + oc);
    float y[Q];
    float s = 0.f;
    #pragma unroll
    for (int j = 0; j < Q; j++) {
        float yy = lrelu(sc_s[oc + j] * vp[j] + sh_s[oc + j]);
        y[j] = yy;
        s += yy * yy;
        xm[(b * COUT + oc + j) * NN + m0 + n] = yy;
    }
    atomicAdd(&hnacc[n], s);
    unsigned short* pr = pk + (size_t)(b * NN + m0 + n) * SK;
    #pragma unroll
    for (int j4 = 0; j4 < Q / 4; j4++) {
        us4 hv, lv;
        #pragma unroll
        for (int j = 0; j < 4; j++) {
            float yy = y[j4 * 4 + j];
            unsigned short h = bf16rn(yy);
            hv[j] = h;
            lv[j] = bf16rn(yy - bf16up(h));
        }
        *(us4*)(pr + oc + j4 * 4) = hv;
        *(us4*)(pr + COUT + oc + j4 * 4) = lv;
    }
    __syncthreads();
    if (tid < 64)
        *(unsigned int*)(pk + (size_t)(b * NN + m0 + tid) * SK + 2 * COUT) =
            __float_as_uint(0.5f * hnacc[tid]);
}

__global__ void head_kernel(const float* __restrict__ hsum8,
                            const float* __restrict__ W2d, const float* __restrict__ b2d,
                            const float* __restrict__ W3d, const float* __restrict__ b3d,
                            const float* __restrict__ W4d, const float* __restrict__ b4d,
                            float* __restrict__ out) {
    __shared__ float h[128], t1[128], t2[64];
    const int t = threadIdx.x;
    float acc = 0.f;
    #pragma unroll
    for (int sl = 0; sl < 8; sl++) acc += hsum8[sl * 128 + t];
    h[t] = acc * (1.f / 32768.f);
    __syncthreads();
    float a = b2d[t];
    for (int j = 0; j < 128; j++) a += W2d[t * 128 + j] * h[j];
    t1[t] = lrelu(a);
    __syncthreads();
    if (t < 64) {
        float a2 = b3d[t];
        for (int j = 0; j < 128; j++) a2 += W3d[t * 128 + j] * t1[j];
        t2[t] = lrelu(a2);
    }
    __syncthreads();
    if (t < 11) {
        float a3 = b4d[t];
        for (int j = 0; j < 64; j++) a3 += W4d[t * 64 + j] * t2[j];
        out[t] = lrelu(a3);
    }
}

extern "C" void kernel_launch(void* const* d_in, const int* in_sizes, int n_in,
                              void* d_out, int out_size, void* d_ws, size_t ws_size,
                              hipStream_t stream) {
    const float* x   = (const float*)d_in[0];
    const float* w1  = (const float*)d_in[1];
    const float* g1  = (const float*)d_in[2];
    const float* b1  = (const float*)d_in[3];
    const float* w2  = (const float*)d_in[4];
    const float* g2  = (const float*)d_in[5];
    const float* b2  = (const float*)d_in[6];
    const float* wd1 = (const float*)d_in[7];
    const float* gd1 = (const float*)d_in[8];
    const float* bd1 = (const float*)d_in[9];
    const float* wd2 = (const float*)d_in[10];
    const float* gd2 = (const float*)d_in[11];
    const float* bd2 = (const float*)d_in[12];
    const float* W2d = (const float*)d_in[13];
    const float* b2d = (const float*)d_in[14];
    const float* W3d = (const float*)d_in[15];
    const float* b3d = (const float*)d_in[16];
    const float* W4d = (const float*)d_in[17];
    const float* b4d = (const float*)d_in[18];
    float* out = (float*)d_out;

    char* ws = (char*)d_ws;
    size_t off = 0;
    auto alloc = [&](size_t bytes) { char* p = ws + off; off += (bytes + 255) & ~size_t(255); return p; };
    int*   idx1  = (int*)  alloc(BB * NN * KK * 4);
    int*   idx2  = (int*)  alloc(BB * NN * KK * 4);
    int*   idx3  = (int*)  alloc(BB * NN * KK * 4);
    float* x1m   = (float*)alloc(BB * 32 * NN * 4);
    float* x2m   = (float*)alloc(BB * 64 * NN * 4);
    float* G1    = (float*)alloc((size_t)BB * NN * 64 * 4);   // contiguous with G2 (pk64 spill)
    float* G2    = (float*)alloc((size_t)BB * NN * 64 * 4);
    float* H     = (float*)alloc((size_t)BB * NN * 64 * 4);
    float* Vbuf  = (float*)alloc((size_t)BB * NN * 64 * 4);
    float* stats = (float*)alloc(4 * 256 * 4);    // 4 slabs: conv1/conv2/convd1/convd2
    float* hsum8 = (float*)alloc(8 * 128 * 4);    // per-XCD mean slabs (contig w/ stats)

    float* st0 = stats;
    float* st1 = stats + 256;
    float* st2 = stats + 512;
    float* st3 = stats + 768;

    // pk placements (all dead-buffer reuse, verified under stream order):
    //  pk3  (2.6MB) -> Vbuf       (Vbuf first written by conv1 stats, after knn3)
    //  pk32 (4.7MB) -> G2         (G2 next written by pre2, after knn32)
    //  pk64 (8.9MB) -> G1 + 0.5MB spill into G2 head (both dead after conv2
    //                  stats; knn64 runs before convd1's precompute rewrites G2)
    unsigned short* pk3  = (unsigned short*)Vbuf;
    unsigned short* pk32 = (unsigned short*)G2;
    unsigned short* pk64 = (unsigned short*)G1;

    const float invP = 1.f / (float)(BB * NN * KK);
    const dim3 knn_grid(NN / 64 * BB);     // 1D: b = id & 7 (XCD pinning)
    const dim3 pre_grid(NN / 64 * BB);

    // one upfront zero: 4 stats slabs (1024) + hsum8 (1024), contiguous.
    zero_kernel<<<8, 256, 0, stream>>>(stats, 1024 + 1024);

    // --- kNN on x (C=3) ---
    pack3_kernel<<<NN / 256 * BB, 256, 0, stream>>>(x, pk3);
    knn_kernel<3><<<knn_grid, 256, 0, stream>>>(x, pk3, idx1);

    // --- conv1: Cout=32, group (x, idx1, C=3), w1 CIN=6 ---
    precompute_kernel<32><<<pre_grid, dim3(32, 8), 2 * 3 * 32 * 4, stream>>>(
        x, 3, w1, 6, 0, 3, G1, H);
    conv_stats_kernel<32, 1><<<NN / 8 * BB, dim3(32, 8), 0, stream>>>(
        G1, idx1, nullptr, nullptr, H, g1, st0, Vbuf);
    applypack_kernel<32><<<pre_grid, 256, 0, stream>>>(Vbuf, st0, g1, b1, x1m, pk32, invP);

    // --- kNN on x1_max (C=32) ---
    knn_kernel<32><<<knn_grid, 256, 0, stream>>>(x1m, pk32, idx2);

    // --- conv2: Cout=64, groups (x, idx1, 3) + (x1m, idx2, 32), w2 CIN=70 ---
    precompute2_kernel<<<pre_grid, dim3(64, 4), 0, stream>>>(x, x1m, w2, G1, G2, H);
    conv_stats_kernel<64, 2><<<NN / 4 * BB, dim3(64, 4), 0, stream>>>(
        G1, idx1, G2, idx2, H, g2, st1, Vbuf);
    applypack_kernel<64><<<pre_grid, 256, 0, stream>>>(Vbuf, st1, g2, b2, x2m, pk64, invP);

    // --- kNN on x2_max (C=64): before convd1 (its precompute clobbers pk64 spill) ---
    knn_kernel<64><<<knn_grid, 256, 0, stream>>>(x2m, pk64, idx3);

    // --- convd1: Cout=64, group (x1m, idx2, 32), wd1 CIN=64 ---
    precompute_kernel<64><<<pre_grid, dim3(64, 4), 2 * 32 * 64 * 4, stream>>>(
        x1m, 32, wd1, 64, 0, 32, G2, H);
    conv_stats_kernel<64, 1><<<NN / 4 * BB, dim3(64, 4), 0, stream>>>(
        G2, idx2, nullptr, nullptr, H, gd1, st2, Vbuf);
    applysum_kernel<<<pre_grid, 256, 0, stream>>>(Vbuf, st2, gd1, bd1, hsum8, invP);

    // --- convd2: Cout=64, group (x2m, idx3, 64), wd2 CIN=128 ---
    precompute_kernel<64><<<pre_grid, dim3(64, 4), 2 * 64 * 64 * 4, stream>>>(
        x2m, 64, wd2, 128, 0, 64, G1, H);
    conv_stats_kernel<64, 1><<<NN / 4 * BB, dim3(64, 4), 0, stream>>>(
        G1, idx3, nullptr, nullptr, H, gd2, st3, Vbuf);
    applysum_kernel<<<pre_grid, 256, 0, stream>>>(Vbuf, st3, gd2, bd2, hsum8, invP);

    // --- MLP head (sums the 8 per-XCD slabs) ---
    head_kernel<<<1, 128, 0, stream>>>(hsum8, W2d, b2d, W3d, b3d, W4d, b4d, out);
}